// Round 1
// 176.485 us; speedup vs baseline: 1.0052x; 1.0052x over previous
//
#include <hip/hip_runtime.h>

typedef __bf16 bf16;
typedef bf16 bf16x4 __attribute__((ext_vector_type(4)));
typedef bf16 bf16x8 __attribute__((ext_vector_type(8)));
typedef float floatx4 __attribute__((ext_vector_type(4)));
typedef float floatx16 __attribute__((ext_vector_type(16)));
typedef unsigned int uintx2 __attribute__((ext_vector_type(2)));

#define NB 8
#define NQ 1024
#define NK 1024
#define DIM 512
#define NH 8
#define DH 64

// async global->LDS, 16B per lane. LDS dest must be wave-uniform base + lane*16B.
__device__ __forceinline__ void async16(const void* g, void* l) {
    __builtin_amdgcn_global_load_lds(
        (const __attribute__((address_space(1))) unsigned int*)(unsigned long long)(g),
        (__attribute__((address_space(3))) unsigned int*)(unsigned long long)(l),
        16, 0, 0);
}

// ---------------------------------------------------------------------------
// prep_fused: blocks [0,4096): cast Q,K fp32->bf16 (float4 vectorized);
//             blocks [4096,4352): Wt[w][n][k] = (bf16)W[k][n], LDS 64x64 tiles.
// ---------------------------------------------------------------------------
__global__ __launch_bounds__(256) void prep_fused(
    const float* __restrict__ Q, const float* __restrict__ K,
    const float* __restrict__ Wq, const float* __restrict__ Wk,
    const float* __restrict__ Wv, const float* __restrict__ Wo,
    bf16* __restrict__ Qb, bf16* __restrict__ Kb, bf16* __restrict__ Wt)
{
    __shared__ bf16 Tl[64][68];
    const int bid = blockIdx.x;
    if (bid < 4096) {
        const int i = bid * 256 + threadIdx.x;   // float4 index
        float4 a = ((const float4*)Q)[i];
        float4 c = ((const float4*)K)[i];
        bf16x4 qa = {(bf16)a.x, (bf16)a.y, (bf16)a.z, (bf16)a.w};
        bf16x4 ka = {(bf16)c.x, (bf16)c.y, (bf16)c.z, (bf16)c.w};
        *(bf16x4*)(Qb + (size_t)i * 4) = qa;
        *(bf16x4*)(Kb + (size_t)i * 4) = ka;
    } else {
        const int bid2 = bid - 4096;
        const int w = bid2 >> 6;
        const int bx = bid2 & 7, by = (bid2 >> 3) & 7;
        const float* W = (w == 0) ? Wq : (w == 1) ? Wk : (w == 2) ? Wv : Wo;
        bf16* out = Wt + (size_t)w * DIM * DIM;
        const int k0 = bx * 64, n0 = by * 64;
        const int tx = threadIdx.x & 15, ty = threadIdx.x >> 4;
        for (int pass = 0; pass < 4; ++pass) {
            int k = ty + pass * 16;
            float4 v = *(const float4*)&W[(size_t)(k0 + k) * DIM + n0 + tx * 4];
            Tl[tx * 4 + 0][k] = (bf16)v.x;
            Tl[tx * 4 + 1][k] = (bf16)v.y;
            Tl[tx * 4 + 2][k] = (bf16)v.z;
            Tl[tx * 4 + 3][k] = (bf16)v.w;
        }
        __syncthreads();
        for (int pass = 0; pass < 4; ++pass) {
            int n = ty + pass * 16;
            bf16x4 ov = *(const bf16x4*)&Tl[n][tx * 4];
            *(bf16x4*)&out[(size_t)(n0 + n) * DIM + k0 + tx * 4] = ov;
        }
    }
}

// ---------------------------------------------------------------------------
// proj_fused: 128x128 tiles, BK=64, XOR-swizzled async staging, m-minor
// block mapping (XCD L2 locality). K-loop LDS double-buffer (attn-style).
// NOTE: LDS buffer selection must be a computed pointer (sh + cur*off) —
// a local array of LDS pointers fails gfx950 codegen (addrspacecast init).
// blocks [0,256):   Q proj -> Qp head layout [b,h,q,64]
// blocks [256,768): KV proj: n<512 -> Kp head layout; n>=512 -> Vpt
//                   [b,h,d,1024] via in-LDS transpose (coalesced stores).
// ---------------------------------------------------------------------------
__global__ __launch_bounds__(256) void proj_fused(
    const bf16* __restrict__ Qb, const bf16* __restrict__ Kb,
    const bf16* __restrict__ Wt,
    const float* __restrict__ bq, const float* __restrict__ bk,
    const float* __restrict__ bv,
    bf16* __restrict__ Qp, bf16* __restrict__ Kp, bf16* __restrict__ Vpt)
{
    __shared__ __attribute__((aligned(16))) bf16 sh[32768];  // 64 KB: A0|A1|B0|B1
    const int t = threadIdx.x;
    const int wave = t >> 6, lane = t & 63, quad = lane >> 4, l16 = lane & 15;
    const int wr = wave >> 1, wc = wave & 1;
    const int bid = blockIdx.x;
    const bool isQ = bid < 256;
    const bf16* A; const bf16* W; int m0, n0;
    if (isQ) { A = Qb; W = Wt;             m0 = (bid & 63) * 128;  n0 = (bid >> 6) * 128; }
    else     { int b2 = bid - 256;
               A = Kb; W = Wt + 512 * DIM; m0 = (b2 & 63) * 128;   n0 = (b2 >> 6) * 128; }

    const int r1 = t >> 3, s1 = t & 7;
    const int p1 = s1 ^ (r1 & 7);          // rows r1+32j keep row&7
    const bf16* aSrc = A + (size_t)(m0 + r1) * DIM + p1 * 8;
    const bf16* wSrc = W + (size_t)(n0 + r1) * DIM + p1 * 8;

    floatx4 acc[4][4];
    for (int i = 0; i < 4; ++i)
        for (int j = 0; j < 4; ++j) acc[i][j] = (floatx4){0.f, 0.f, 0.f, 0.f};

    // prologue: issue kt=0 into buf 0 (A at sh+0, B at sh+16384)
    #pragma unroll
    for (int j = 0; j < 4; ++j) {
        async16(aSrc + (size_t)j * 32 * DIM, sh + (t + j * 256) * 8);
        async16(wSrc + (size_t)j * 32 * DIM, sh + 16384 + (t + j * 256) * 8);
    }

    for (int kt = 0; kt < 8; ++kt) {
        __syncthreads();   // tile kt loads done; all waves done with other buf
        const int cur = kt & 1;
        bf16* Acur = sh + cur * 8192;
        bf16* Bcur = sh + 16384 + cur * 8192;
        if (kt < 7) {
            bf16* Anxt = sh + (1 - cur) * 8192;
            bf16* Bnxt = sh + 16384 + (1 - cur) * 8192;
            const int ko = (kt + 1) * 64;
            #pragma unroll
            for (int j = 0; j < 4; ++j) {
                async16(aSrc + ko + (size_t)j * 32 * DIM, Anxt + (t + j * 256) * 8);
                async16(wSrc + ko + (size_t)j * 32 * DIM, Bnxt + (t + j * 256) * 8);
            }
        }
        #pragma unroll
        for (int ks = 0; ks < 2; ++ks) {
            bf16x8 af[4], bfr[4];
            #pragma unroll
            for (int mi = 0; mi < 4; ++mi) {
                const int row = wr * 64 + mi * 16 + l16;
                af[mi] = *(const bf16x8*)(Acur + row * 64 + (((ks * 4 + quad) ^ (row & 7)) << 3));
            }
            #pragma unroll
            for (int ni = 0; ni < 4; ++ni) {
                const int row = wc * 64 + ni * 16 + l16;
                bfr[ni] = *(const bf16x8*)(Bcur + row * 64 + (((ks * 4 + quad) ^ (row & 7)) << 3));
            }
            #pragma unroll
            for (int mi = 0; mi < 4; ++mi)
                #pragma unroll
                for (int ni = 0; ni < 4; ++ni)
                    acc[mi][ni] = __builtin_amdgcn_mfma_f32_16x16x32_bf16(
                        af[mi], bfr[ni], acc[mi][ni], 0, 0, 0);
        }
    }

    const bool isV = (!isQ) && (n0 >= 512);
    if (!isV) {
        bf16* out = isQ ? Qp : Kp;
        const float* bias = isQ ? bq : bk;
        for (int ni = 0; ni < 4; ++ni) {
            const int n = n0 + wc * 64 + ni * 16 + l16;
            const float bb = bias[n];
            const int hd = n >> 6, d = n & 63;
            for (int mi = 0; mi < 4; ++mi) {
                for (int r = 0; r < 4; ++r) {
                    const int m = m0 + wr * 64 + mi * 16 + quad * 4 + r;
                    const int b = m >> 10, q = m & 1023;
                    out[((size_t)(b * 8 + hd) * 1024 + q) * 64 + d] = (bf16)(acc[mi][ni][r] + bb);
                }
            }
        }
    } else {
        // dump tile (+bias) to LDS as Tb[n][m] (first 32 KB of sh) with
        // chunk-XOR swizzle, then store coalesced rows of Vpt [b,h,d,1024]
        __syncthreads();
        for (int ni = 0; ni < 4; ++ni) {
            const int n = wc * 64 + ni * 16 + l16;           // local n
            const float bb = bv[n0 + n - 512];
            for (int mi = 0; mi < 4; ++mi) {
                const int mb = wr * 64 + mi * 16 + quad * 4;  // local m base (r=0..3)
                const int slot = ((mb >> 3) ^ (n & 15));
                bf16x4 pk = {(bf16)(acc[mi][ni][0] + bb), (bf16)(acc[mi][ni][1] + bb),
                             (bf16)(acc[mi][ni][2] + bb), (bf16)(acc[mi][ni][3] + bb)};
                *(bf16x4*)(sh + n * 128 + slot * 8 + (mb & 7)) = pk;
            }
        }
        __syncthreads();
        const int n = t >> 1, hf = t & 1;
        const int nv = n0 + n - 512, hd = nv >> 6, d = nv & 63;
        const int b = m0 >> 10, qb = m0 & 1023;
        bf16* dst = Vpt + ((size_t)(b * 8 + hd) * 64 + d) * 1024 + qb + hf * 64;
        #pragma unroll
        for (int j = 0; j < 8; ++j) {
            const int ch = hf * 8 + j;
            const int slot = ch ^ (n & 15);
            bf16x8 v8 = *(const bf16x8*)(sh + n * 128 + slot * 8);
            *(bf16x8*)(dst + j * 8) = v8;
        }
    }
}

// ---------------------------------------------------------------------------
// attn: flash attention per (b,h). 512 blocks x 4 waves, 128 q/block,
// 32 q/wave via 32x32x16 MFMA. Swapped QK^T (S^T = K Q^T) puts a full
// q-row's P in lane-local regs (col=lane&31=q); P feeds PV in-register
// via cvt+permlane32_swap (no P LDS round-trip). PV computes O^T = V^T P^T.
// exp2-domain softmax (scale*log2e folded), no max-subtraction (bounded S).
// K/V LDS double-buffer via global_load_lds w/ pre-swizzled source.
// ---------------------------------------------------------------------------
__global__ __launch_bounds__(256) void attn_kernel(
    const bf16* __restrict__ Qp, const bf16* __restrict__ Kp,
    const bf16* __restrict__ Vpt, const int* __restrict__ mask,
    bf16* __restrict__ Oa)
{
    const int bh = blockIdx.x & 63, qblk = blockIdx.x >> 6;  // qblk 0..7
    const int b = bh >> 3, hd = bh & 7;
    const int t = threadIdx.x;
    const int wave = t >> 6, lane = t & 63;
    const int l31 = lane & 31, hi = lane >> 5;
    const float SC = 1.8033688f;   // 1/(sqrt(64)*0.1) * log2(e)

    __shared__ __attribute__((aligned(16))) bf16 Kt[2][64 * 64];
    __shared__ __attribute__((aligned(16))) bf16 Vt[2][64 * 64];

    const bf16* Qbase = Qp + ((size_t)bh * NQ + qblk * 128 + wave * 32) * DH;
    const bf16* Kbase = Kp + (size_t)bh * NK * DH;
    const bf16* Vbase = Vpt + (size_t)bh * DH * NK;
    const int* mrow = mask + b * NK;

    // Q B-frags (q=l31, step st covers d = st*16 + hi*8 + j), kept in regs
    bf16x8 qf[4];
    #pragma unroll
    for (int st = 0; st < 4; ++st)
        qf[st] = *(const bf16x8*)(Qbase + (size_t)l31 * DH + st * 16 + hi * 8);

    // O^T acc: col=q=l31; row d = dsub*32 + (r&3) + 8*(r>>2) + 4*hi
    floatx16 o[2];
    #pragma unroll
    for (int d = 0; d < 2; ++d)
        #pragma unroll
        for (int i = 0; i < 16; ++i) o[d][i] = 0.f;
    float lsum = 0.f;

    const int r1 = t >> 3, s1 = t & 7;
    const int p1 = s1 ^ (r1 & 7);          // (r1+32)&7 == r1&7
    const bf16* kSrc = Kbase + r1 * 64 + p1 * 8;            // + kt*4096
    const bf16* vSrc = Vbase + (size_t)r1 * 1024 + p1 * 8;  // + kt*64

    // prologue: issue tile 0 into buf 0
    async16(kSrc, Kt[0] + t * 8);
    async16(kSrc + 32 * 64, Kt[0] + (t + 256) * 8);
    async16(vSrc, Vt[0] + t * 8);
    async16(vSrc + (size_t)32 * 1024, Vt[0] + (t + 256) * 8);

    for (int kt = 0; kt < NK / 64; ++kt) {
        __syncthreads();   // tile kt loads complete; all waves done with other buf
        const int cur = kt & 1;
        if (kt < NK / 64 - 1) {
            const int nxt = 1 - cur;
            async16(kSrc + (kt + 1) * 4096, Kt[nxt] + t * 8);
            async16(kSrc + (kt + 1) * 4096 + 32 * 64, Kt[nxt] + (t + 256) * 8);
            async16(vSrc + (kt + 1) * 64, Vt[nxt] + t * 8);
            async16(vSrc + (kt + 1) * 64 + (size_t)32 * 1024, Vt[nxt] + (t + 256) * 8);
        }

        // QK^T: per 32-key subtile, S^T[key][q] = sum_d K[key][d] Q^T[d][q]
        // A = K rows (row=key=l31+sub*32, k=d), B = qf. C: col=q, row=key.
        floatx16 sf[2];
        __builtin_amdgcn_s_setprio(1);
        #pragma unroll
        for (int sub = 0; sub < 2; ++sub) {
            floatx16 s;
            #pragma unroll
            for (int i = 0; i < 16; ++i) s[i] = 0.f;
            const int row = sub * 32 + l31;
            #pragma unroll
            for (int st = 0; st < 4; ++st) {
                bf16x8 ka = *(const bf16x8*)(Kt[cur] + row * 64 +
                                             (((st * 2 + hi) ^ (row & 7)) << 3));
                s = __builtin_amdgcn_mfma_f32_32x32x16_bf16(ka, qf[st], s, 0, 0, 0);
            }
            sf[sub] = s;
        }
        __builtin_amdgcn_s_setprio(0);

        // mask + exp2 + pack: reg r -> key (r&3)+8*(r>>2)+4*hi (+32*sub).
        // w[sub][m][rr] = packed bf16 pair for keys 8m+4hi+2rr, +1.
        unsigned int w[2][4][2];
        #pragma unroll
        for (int sub = 0; sub < 2; ++sub)
            #pragma unroll
            for (int m = 0; m < 4; ++m) {
                const int4 m4 = *(const int4*)&mrow[kt * 64 + sub * 32 + m * 8 + hi * 4];
                const float md0 = m4.x ? 0.f : -1.0e38f;
                const float md1 = m4.y ? 0.f : -1.0e38f;
                const float md2 = m4.z ? 0.f : -1.0e38f;
                const float md3 = m4.w ? 0.f : -1.0e38f;
                const float p0 = __builtin_amdgcn_exp2f(sf[sub][m * 4 + 0] * SC + md0);
                const float p1 = __builtin_amdgcn_exp2f(sf[sub][m * 4 + 1] * SC + md1);
                const float p2 = __builtin_amdgcn_exp2f(sf[sub][m * 4 + 2] * SC + md2);
                const float p3 = __builtin_amdgcn_exp2f(sf[sub][m * 4 + 3] * SC + md3);
                lsum += (p0 + p1) + (p2 + p3);
                union { bf16 h[2]; unsigned int u; } pkA, pkB;
                pkA.h[0] = (bf16)p0; pkA.h[1] = (bf16)p1;
                pkB.h[0] = (bf16)p2; pkB.h[1] = (bf16)p3;
                w[sub][m][0] = pkA.u;
                w[sub][m][1] = pkB.u;
            }

        // PV: O^T[d][q] += sum_k V^T[d][k] P^T[k][q] in 16-key steps.
        // B-frag (P^T) built in-register: permlane32_swap of (w[2ks], w[2ks+1])
        // gives word t=rr (r[0]) and t=2+rr (r[1]) for both lane halves.
        __builtin_amdgcn_s_setprio(1);
        #pragma unroll
        for (int sub = 0; sub < 2; ++sub)
            #pragma unroll
            for (int ks = 0; ks < 2; ++ks) {
                uintx2 e0 = __builtin_amdgcn_permlane32_swap(
                    w[sub][2 * ks + 0][0], w[sub][2 * ks + 1][0], false, false);
                uintx2 e1 = __builtin_amdgcn_permlane32_swap(
                    w[sub][2 * ks + 0][1], w[sub][2 * ks + 1][1], false, false);
                union { unsigned int u[4]; bf16x8 v; } pb;
                pb.u[0] = e0[0]; pb.u[1] = e1[0]; pb.u[2] = e0[1]; pb.u[3] = e1[1];
                const int kc = sub * 2 + ks;   // 16-key step index 0..3
                #pragma unroll
                for (int dsub = 0; dsub < 2; ++dsub) {
                    const int row = dsub * 32 + l31;
                    bf16x8 va = *(const bf16x8*)(Vt[cur] + row * 64 +
                                                 (((kc * 2 + hi) ^ (row & 7)) << 3));
                    o[dsub] = __builtin_amdgcn_mfma_f32_32x32x16_bf16(va, pb.v, o[dsub], 0, 0, 0);
                }
            }
        __builtin_amdgcn_s_setprio(0);
    }

    // denominator: lane and lane+32 hold complementary key-halves of row q=l31
    lsum += __shfl_xor(lsum, 32, 64);
    const float inv = 1.f / lsum;
    const int q = qblk * 128 + wave * 32 + l31;
    bf16* orow = Oa + ((size_t)(b * NQ + q)) * DIM + hd * 64;
    #pragma unroll
    for (int dsub = 0; dsub < 2; ++dsub)
        #pragma unroll
        for (int rg = 0; rg < 4; ++rg) {
            bf16x4 st = {(bf16)(o[dsub][rg * 4 + 0] * inv), (bf16)(o[dsub][rg * 4 + 1] * inv),
                         (bf16)(o[dsub][rg * 4 + 2] * inv), (bf16)(o[dsub][rg * 4 + 3] * inv)};
            *(bf16x4*)(orow + dsub * 32 + rg * 8 + hi * 4) = st;
        }
}

// ---------------------------------------------------------------------------
// ffn_gemm: 128x128 tile, BK=64, XOR-swizzled staging, m-minor mapping,
// K-loop double-buffer (computed LDS pointers — see proj note).
// Yb (bf16) = Oa + relu(Oa @ Wo^T + bo). 256 blocks.
// ---------------------------------------------------------------------------
__global__ __launch_bounds__(256) void ffn_gemm(
    const bf16* __restrict__ Oa, const bf16* __restrict__ W,
    const float* __restrict__ bias, bf16* __restrict__ Yb)
{
    __shared__ __attribute__((aligned(16))) bf16 sh[32768];  // 64 KB: A0|A1|B0|B1
    const int t = threadIdx.x;
    const int wave = t >> 6, lane = t & 63, quad = lane >> 4, l16 = lane & 15;
    const int wr = wave >> 1, wc = wave & 1;
    const int m0 = (blockIdx.x & 63) * 128, n0 = (blockIdx.x >> 6) * 128;

    const int r1 = t >> 3, s1 = t & 7;
    const int p1 = s1 ^ (r1 & 7);
    const bf16* aSrc = Oa + (size_t)(m0 + r1) * DIM + p1 * 8;
    const bf16* wSrc = W  + (size_t)(n0 + r1) * DIM + p1 * 8;

    floatx4 acc[4][4];
    for (int i = 0; i < 4; ++i)
        for (int j = 0; j < 4; ++j) acc[i][j] = (floatx4){0.f, 0.f, 0.f, 0.f};

    #pragma unroll
    for (int j = 0; j < 4; ++j) {
        async16(aSrc + (size_t)j * 32 * DIM, sh + (t + j * 256) * 8);
        async16(wSrc + (size_t)j * 32 * DIM, sh + 16384 + (t + j * 256) * 8);
    }

    for (int kt = 0; kt < 8; ++kt) {
        __syncthreads();
        const int cur = kt & 1;
        bf16* Acur = sh + cur * 8192;
        bf16* Bcur = sh + 16384 + cur * 8192;
        if (kt < 7) {
            bf16* Anxt = sh + (1 - cur) * 8192;
            bf16* Bnxt = sh + 16384 + (1 - cur) * 8192;
            const int ko = (kt + 1) * 64;
            #pragma unroll
            for (int j = 0; j < 4; ++j) {
                async16(aSrc + ko + (size_t)j * 32 * DIM, Anxt + (t + j * 256) * 8);
                async16(wSrc + ko + (size_t)j * 32 * DIM, Bnxt + (t + j * 256) * 8);
            }
        }
        #pragma unroll
        for (int ks = 0; ks < 2; ++ks) {
            bf16x8 af[4], bfr[4];
            #pragma unroll
            for (int mi = 0; mi < 4; ++mi) {
                const int row = wr * 64 + mi * 16 + l16;
                af[mi] = *(const bf16x8*)(Acur + row * 64 + (((ks * 4 + quad) ^ (row & 7)) << 3));
            }
            #pragma unroll
            for (int ni = 0; ni < 4; ++ni) {
                const int row = wc * 64 + ni * 16 + l16;
                bfr[ni] = *(const bf16x8*)(Bcur + row * 64 + (((ks * 4 + quad) ^ (row & 7)) << 3));
            }
            #pragma unroll
            for (int mi = 0; mi < 4; ++mi)
                #pragma unroll
                for (int ni = 0; ni < 4; ++ni)
                    acc[mi][ni] = __builtin_amdgcn_mfma_f32_16x16x32_bf16(
                        af[mi], bfr[ni], acc[mi][ni], 0, 0, 0);
        }
    }

    for (int ni = 0; ni < 4; ++ni) {
        const int n = n0 + wc * 64 + ni * 16 + l16;
        const float bb = bias[n];
        for (int mi = 0; mi < 4; ++mi) {
            for (int r = 0; r < 4; ++r) {
                const int m = m0 + wr * 64 + mi * 16 + quad * 4 + r;
                const float ov = (float)Oa[(size_t)m * DIM + n];
                Yb[(size_t)m * DIM + n] = (bf16)(ov + fmaxf(acc[mi][ni][r] + bb, 0.f));
            }
        }
    }
}

// ---------------------------------------------------------------------------
// ln: LayerNorm over last dim (512). One wave per row; bf16 in, fp32 out.
// Each lane owns 8 contiguous cols (one bf16x8 load).
// ---------------------------------------------------------------------------
__global__ __launch_bounds__(256) void ln_kernel(
    const bf16* __restrict__ Y, const float* __restrict__ gamma,
    const float* __restrict__ beta, float* __restrict__ out)
{
    const int row  = blockIdx.x * 4 + (threadIdx.x >> 6);
    const int lane = threadIdx.x & 63;
    bf16x8 v = *(const bf16x8*)(Y + (size_t)row * DIM + lane * 8);
    float f[8];
    float s = 0.f, sq = 0.f;
    #pragma unroll
    for (int j = 0; j < 8; ++j) {
        f[j] = (float)v[j];
        s += f[j];
        sq += f[j] * f[j];
    }
    for (int mk = 32; mk >= 1; mk >>= 1) {
        s  += __shfl_xor(s,  mk, 64);
        sq += __shfl_xor(sq, mk, 64);
    }
    const float mu  = s * (1.f / 512.f);
    const float var = sq * (1.f / 512.f) - mu * mu;
    const float inv = rsqrtf(var + 1e-5f);
    float4 g1 = ((const float4*)gamma)[lane * 2];
    float4 g2 = ((const float4*)gamma)[lane * 2 + 1];
    float4 b1 = ((const float4*)beta)[lane * 2];
    float4 b2 = ((const float4*)beta)[lane * 2 + 1];
    float4 o1, o2;
    o1.x = (f[0] - mu) * inv * g1.x + b1.x;
    o1.y = (f[1] - mu) * inv * g1.y + b1.y;
    o1.z = (f[2] - mu) * inv * g1.z + b1.z;
    o1.w = (f[3] - mu) * inv * g1.w + b1.w;
    o2.x = (f[4] - mu) * inv * g2.x + b2.x;
    o2.y = (f[5] - mu) * inv * g2.y + b2.y;
    o2.z = (f[6] - mu) * inv * g2.z + b2.z;
    o2.w = (f[7] - mu) * inv * g2.w + b2.w;
    float* orow = out + (size_t)row * DIM;
    ((float4*)orow)[lane * 2]     = o1;
    ((float4*)orow)[lane * 2 + 1] = o2;
}

// ---------------------------------------------------------------------------
extern "C" void kernel_launch(void* const* d_in, const int* in_sizes, int n_in,
                              void* d_out, int out_size, void* d_ws, size_t ws_size,
                              hipStream_t stream) {
    const float* Q  = (const float*)d_in[0];
    const float* K  = (const float*)d_in[1];
    const int*   mask = (const int*)d_in[2];
    const float* Wq = (const float*)d_in[3];
    const float* bq = (const float*)d_in[4];
    const float* Wk = (const float*)d_in[5];
    const float* bk = (const float*)d_in[6];
    const float* Wv = (const float*)d_in[7];
    const float* bv = (const float*)d_in[8];
    const float* Wo = (const float*)d_in[9];
    const float* bo = (const float*)d_in[10];
    const float* gamma = (const float*)d_in[11];
    const float* beta  = (const float*)d_in[12];

    char* ws = (char*)d_ws;
    bf16* Wt  = (bf16*)(ws);                   // 2 MB (4 x 512x512 bf16, transposed)
    bf16* Qb  = (bf16*)(ws + 2097152);         // 8 MB
    bf16* Kb  = (bf16*)(ws + 10485760);        // 8 MB
    bf16* Qp  = (bf16*)(ws + 18874368);        // 8 MB  [b,h,q,64]
    bf16* Kp  = (bf16*)(ws + 27262976);        // 8 MB  [b,h,k,64]
    bf16* Vpt = (bf16*)(ws + 35651584);        // 8 MB  [b,h,d,1024]
    bf16* Oa  = (bf16*)(ws + 44040192);        // 8 MB  [b,q,512]
    bf16* Yb  = (bf16*)(ws + 52428800);        // 8 MB  [b,q,512] bf16
    float* out = (float*)d_out;

    prep_fused<<<4352, 256, 0, stream>>>(Q, K, Wq, Wk, Wv, Wo, Qb, Kb, Wt);
    proj_fused<<<768, 256, 0, stream>>>(Qb, Kb, Wt, bq, bk, bv, Qp, Kp, Vpt);
    attn_kernel<<<512, 256, 0, stream>>>(Qp, Kp, Vpt, mask, Oa);
    ffn_gemm<<<256, 256, 0, stream>>>(Oa, Wt + 3 * 262144, bo, Yb);
    ln_kernel<<<2048, 256, 0, stream>>>(Yb, gamma, beta, out);
}

// Round 2
// 170.406 us; speedup vs baseline: 1.0411x; 1.0357x over previous
//
#include <hip/hip_runtime.h>

typedef __bf16 bf16;
typedef bf16 bf16x4 __attribute__((ext_vector_type(4)));
typedef bf16 bf16x8 __attribute__((ext_vector_type(8)));
typedef float floatx4 __attribute__((ext_vector_type(4)));

#define NB 8
#define NQ 1024
#define NK 1024
#define DIM 512
#define NH 8
#define DH 64

// async global->LDS, 16B per lane. LDS dest must be wave-uniform base + lane*16B.
__device__ __forceinline__ void async16(const void* g, void* l) {
    __builtin_amdgcn_global_load_lds(
        (const __attribute__((address_space(1))) unsigned int*)(unsigned long long)(g),
        (__attribute__((address_space(3))) unsigned int*)(unsigned long long)(l),
        16, 0, 0);
}

// ---------------------------------------------------------------------------
// prep_fused: blocks [0,4096): cast Q,K fp32->bf16 (float4 vectorized);
//             blocks [4096,4352): Wt[w][n][k] = (bf16)W[k][n], LDS 64x64 tiles.
// ---------------------------------------------------------------------------
__global__ __launch_bounds__(256) void prep_fused(
    const float* __restrict__ Q, const float* __restrict__ K,
    const float* __restrict__ Wq, const float* __restrict__ Wk,
    const float* __restrict__ Wv, const float* __restrict__ Wo,
    bf16* __restrict__ Qb, bf16* __restrict__ Kb, bf16* __restrict__ Wt)
{
    __shared__ bf16 Tl[64][68];
    const int bid = blockIdx.x;
    if (bid < 4096) {
        const int i = bid * 256 + threadIdx.x;   // float4 index
        float4 a = ((const float4*)Q)[i];
        float4 c = ((const float4*)K)[i];
        bf16x4 qa = {(bf16)a.x, (bf16)a.y, (bf16)a.z, (bf16)a.w};
        bf16x4 ka = {(bf16)c.x, (bf16)c.y, (bf16)c.z, (bf16)c.w};
        *(bf16x4*)(Qb + (size_t)i * 4) = qa;
        *(bf16x4*)(Kb + (size_t)i * 4) = ka;
    } else {
        const int bid2 = bid - 4096;
        const int w = bid2 >> 6;
        const int bx = bid2 & 7, by = (bid2 >> 3) & 7;
        const float* W = (w == 0) ? Wq : (w == 1) ? Wk : (w == 2) ? Wv : Wo;
        bf16* out = Wt + (size_t)w * DIM * DIM;
        const int k0 = bx * 64, n0 = by * 64;
        const int tx = threadIdx.x & 15, ty = threadIdx.x >> 4;
        for (int pass = 0; pass < 4; ++pass) {
            int k = ty + pass * 16;
            float4 v = *(const float4*)&W[(size_t)(k0 + k) * DIM + n0 + tx * 4];
            Tl[tx * 4 + 0][k] = (bf16)v.x;
            Tl[tx * 4 + 1][k] = (bf16)v.y;
            Tl[tx * 4 + 2][k] = (bf16)v.z;
            Tl[tx * 4 + 3][k] = (bf16)v.w;
        }
        __syncthreads();
        for (int pass = 0; pass < 4; ++pass) {
            int n = ty + pass * 16;
            bf16x4 ov = *(const bf16x4*)&Tl[n][tx * 4];
            *(bf16x4*)&out[(size_t)(n0 + n) * DIM + k0 + tx * 4] = ov;
        }
    }
}

// ---------------------------------------------------------------------------
// proj_fused: 128x128 tiles, BK=64, XOR-swizzled async staging, m-minor
// block mapping (XCD L2 locality). K-loop LDS double-buffer (attn-style).
// NOTE: LDS buffer selection must be a computed pointer (sh + cur*off) —
// a local array of LDS pointers fails gfx950 codegen (addrspacecast init).
// blocks [0,256):   Q proj -> Qp head layout [b,h,q,64]
// blocks [256,768): KV proj: n<512 -> Kp head layout; n>=512 -> Vpt
//                   [b,h,d,1024] via in-LDS transpose (coalesced stores).
// ---------------------------------------------------------------------------
__global__ __launch_bounds__(256) void proj_fused(
    const bf16* __restrict__ Qb, const bf16* __restrict__ Kb,
    const bf16* __restrict__ Wt,
    const float* __restrict__ bq, const float* __restrict__ bk,
    const float* __restrict__ bv,
    bf16* __restrict__ Qp, bf16* __restrict__ Kp, bf16* __restrict__ Vpt)
{
    __shared__ __attribute__((aligned(16))) bf16 sh[32768];  // 64 KB: A0|A1|B0|B1
    const int t = threadIdx.x;
    const int wave = t >> 6, lane = t & 63, quad = lane >> 4, l16 = lane & 15;
    const int wr = wave >> 1, wc = wave & 1;
    const int bid = blockIdx.x;
    const bool isQ = bid < 256;
    const bf16* A; const bf16* W; int m0, n0;
    if (isQ) { A = Qb; W = Wt;             m0 = (bid & 63) * 128;  n0 = (bid >> 6) * 128; }
    else     { int b2 = bid - 256;
               A = Kb; W = Wt + 512 * DIM; m0 = (b2 & 63) * 128;   n0 = (b2 >> 6) * 128; }

    const int r1 = t >> 3, s1 = t & 7;
    const int p1 = s1 ^ (r1 & 7);          // rows r1+32j keep row&7
    const bf16* aSrc = A + (size_t)(m0 + r1) * DIM + p1 * 8;
    const bf16* wSrc = W + (size_t)(n0 + r1) * DIM + p1 * 8;

    floatx4 acc[4][4];
    for (int i = 0; i < 4; ++i)
        for (int j = 0; j < 4; ++j) acc[i][j] = (floatx4){0.f, 0.f, 0.f, 0.f};

    // prologue: issue kt=0 into buf 0 (A at sh+0, B at sh+16384)
    #pragma unroll
    for (int j = 0; j < 4; ++j) {
        async16(aSrc + (size_t)j * 32 * DIM, sh + (t + j * 256) * 8);
        async16(wSrc + (size_t)j * 32 * DIM, sh + 16384 + (t + j * 256) * 8);
    }

    for (int kt = 0; kt < 8; ++kt) {
        __syncthreads();   // tile kt loads done; all waves done with other buf
        const int cur = kt & 1;
        bf16* Acur = sh + cur * 8192;
        bf16* Bcur = sh + 16384 + cur * 8192;
        if (kt < 7) {
            bf16* Anxt = sh + (1 - cur) * 8192;
            bf16* Bnxt = sh + 16384 + (1 - cur) * 8192;
            const int ko = (kt + 1) * 64;
            #pragma unroll
            for (int j = 0; j < 4; ++j) {
                async16(aSrc + ko + (size_t)j * 32 * DIM, Anxt + (t + j * 256) * 8);
                async16(wSrc + ko + (size_t)j * 32 * DIM, Bnxt + (t + j * 256) * 8);
            }
        }
        #pragma unroll
        for (int ks = 0; ks < 2; ++ks) {
            bf16x8 af[4], bfr[4];
            #pragma unroll
            for (int mi = 0; mi < 4; ++mi) {
                const int row = wr * 64 + mi * 16 + l16;
                af[mi] = *(const bf16x8*)(Acur + row * 64 + (((ks * 4 + quad) ^ (row & 7)) << 3));
            }
            #pragma unroll
            for (int ni = 0; ni < 4; ++ni) {
                const int row = wc * 64 + ni * 16 + l16;
                bfr[ni] = *(const bf16x8*)(Bcur + row * 64 + (((ks * 4 + quad) ^ (row & 7)) << 3));
            }
            #pragma unroll
            for (int mi = 0; mi < 4; ++mi)
                #pragma unroll
                for (int ni = 0; ni < 4; ++ni)
                    acc[mi][ni] = __builtin_amdgcn_mfma_f32_16x16x32_bf16(
                        af[mi], bfr[ni], acc[mi][ni], 0, 0, 0);
        }
    }

    const bool isV = (!isQ) && (n0 >= 512);
    if (!isV) {
        bf16* out = isQ ? Qp : Kp;
        const float* bias = isQ ? bq : bk;
        for (int ni = 0; ni < 4; ++ni) {
            const int n = n0 + wc * 64 + ni * 16 + l16;
            const float bb = bias[n];
            const int hd = n >> 6, d = n & 63;
            for (int mi = 0; mi < 4; ++mi) {
                for (int r = 0; r < 4; ++r) {
                    const int m = m0 + wr * 64 + mi * 16 + quad * 4 + r;
                    const int b = m >> 10, q = m & 1023;
                    out[((size_t)(b * 8 + hd) * 1024 + q) * 64 + d] = (bf16)(acc[mi][ni][r] + bb);
                }
            }
        }
    } else {
        // dump tile (+bias) to LDS as Tb[n][m] (first 32 KB of sh) with
        // chunk-XOR swizzle, then store coalesced rows of Vpt [b,h,d,1024]
        __syncthreads();
        for (int ni = 0; ni < 4; ++ni) {
            const int n = wc * 64 + ni * 16 + l16;           // local n
            const float bb = bv[n0 + n - 512];
            for (int mi = 0; mi < 4; ++mi) {
                const int mb = wr * 64 + mi * 16 + quad * 4;  // local m base (r=0..3)
                const int slot = ((mb >> 3) ^ (n & 15));
                bf16x4 pk = {(bf16)(acc[mi][ni][0] + bb), (bf16)(acc[mi][ni][1] + bb),
                             (bf16)(acc[mi][ni][2] + bb), (bf16)(acc[mi][ni][3] + bb)};
                *(bf16x4*)(sh + n * 128 + slot * 8 + (mb & 7)) = pk;
            }
        }
        __syncthreads();
        const int n = t >> 1, hf = t & 1;
        const int nv = n0 + n - 512, hd = nv >> 6, d = nv & 63;
        const int b = m0 >> 10, qb = m0 & 1023;
        bf16* dst = Vpt + ((size_t)(b * 8 + hd) * 64 + d) * 1024 + qb + hf * 64;
        #pragma unroll
        for (int j = 0; j < 8; ++j) {
            const int ch = hf * 8 + j;
            const int slot = ch ^ (n & 15);
            bf16x8 v8 = *(const bf16x8*)(sh + n * 128 + slot * 8);
            *(bf16x8*)(dst + j * 8) = v8;
        }
    }
}

// ---------------------------------------------------------------------------
// attn: flash attention per (b,h). 1024 blocks x 4 waves, 64 q/block,
// 16 q/wave (halved from 32 to double occupancy: 4096 waves = 4/SIMD,
// LDS 40KB -> exactly 4 blocks/CU resident). 16x16x32 MFMA, S^T trick
// (A=K, B=Q) -> packed b64 P writes (conflict-free quad-spread K/V reads).
// exp2-domain softmax (scale*log2e folded). K/V LDS double-buffer.
// ---------------------------------------------------------------------------
__global__ __launch_bounds__(256) void attn_kernel(
    const bf16* __restrict__ Qp, const bf16* __restrict__ Kp,
    const bf16* __restrict__ Vpt, const int* __restrict__ mask,
    bf16* __restrict__ Oa)
{
    const int bh = blockIdx.x & 63, qblk = blockIdx.x >> 6;  // qblk 0..15
    const int b = bh >> 3, hd = bh & 7;
    const int t = threadIdx.x;
    const int wave = t >> 6, lane = t & 63, quad = lane >> 4, l16 = lane & 15;
    const float SC = 1.8033688f;   // 1/(sqrt(64)*0.1) * log2(e)

    __shared__ __attribute__((aligned(16))) bf16 Kt[2][64 * 64];
    __shared__ __attribute__((aligned(16))) bf16 Vt[2][64 * 64];
    __shared__ __attribute__((aligned(16))) bf16 Pl[4][16 * 64];

    const bf16* Qbase = Qp + ((size_t)bh * NQ + qblk * 64 + wave * 16) * DH;
    const bf16* Kbase = Kp + (size_t)bh * NK * DH;
    const bf16* Vbase = Vpt + (size_t)bh * DH * NK;
    const int* mrow = mask + b * NK;

    // Q B-frags (col=q=l16, k = hh*32 + quad*8 + j), kept in regs
    bf16x8 qf[2];
    #pragma unroll
    for (int hh = 0; hh < 2; ++hh)
        qf[hh] = *(const bf16x8*)(Qbase + (size_t)l16 * DH + hh * 32 + quad * 8);

    floatx4 o[4];
    float lsum = 0.f;
    #pragma unroll
    for (int i = 0; i < 4; ++i) o[i] = (floatx4){0.f, 0.f, 0.f, 0.f};

    const int r1 = t >> 3, s1 = t & 7;
    const int p1 = s1 ^ (r1 & 7);          // (r1+32)&7 == r1&7
    const bf16* kSrc = Kbase + r1 * 64 + p1 * 8;            // + kt*4096
    const bf16* vSrc = Vbase + (size_t)r1 * 1024 + p1 * 8;  // + kt*64

    // prologue: issue tile 0 into buf 0
    async16(kSrc, Kt[0] + t * 8);
    async16(kSrc + 32 * 64, Kt[0] + (t + 256) * 8);
    async16(vSrc, Vt[0] + t * 8);
    async16(vSrc + (size_t)32 * 1024, Vt[0] + (t + 256) * 8);

    for (int kt = 0; kt < NK / 64; ++kt) {
        __syncthreads();   // tile kt loads complete; all waves done with other buf
        const int cur = kt & 1;
        if (kt < NK / 64 - 1) {
            const int nxt = 1 - cur;
            async16(kSrc + (kt + 1) * 4096, Kt[nxt] + t * 8);
            async16(kSrc + (kt + 1) * 4096 + 32 * 64, Kt[nxt] + (t + 256) * 8);
            async16(vSrc + (kt + 1) * 64, Vt[nxt] + t * 8);
            async16(vSrc + (kt + 1) * 64 + (size_t)32 * 1024, Vt[nxt] + (t + 256) * 8);
        }

        // K A-frags (lane = key-within-subtile), conflict-free quad-spread
        bf16x8 kb[4][2];
        #pragma unroll
        for (int sub = 0; sub < 4; ++sub) {
            const int rowk = sub * 16 + l16;
            kb[sub][0] = *(const bf16x8*)(Kt[cur] + rowk * 64 + ((quad ^ (rowk & 7)) << 3));
            kb[sub][1] = *(const bf16x8*)(Kt[cur] + rowk * 64 + (((quad + 4) ^ (rowk & 7)) << 3));
        }
        // S^T = K Q^T: C col = q (l16), row = key-within-sub (quad*4+r)
        floatx4 sf[4];
        __builtin_amdgcn_s_setprio(1);
        #pragma unroll
        for (int sub = 0; sub < 4; ++sub) {
            floatx4 s = {0.f, 0.f, 0.f, 0.f};
            s = __builtin_amdgcn_mfma_f32_16x16x32_bf16(kb[sub][0], qf[0], s, 0, 0, 0);
            s = __builtin_amdgcn_mfma_f32_16x16x32_bf16(kb[sub][1], qf[1], s, 0, 0, 0);
            sf[sub] = s;
        }
        __builtin_amdgcn_s_setprio(0);
        // exp2 + mask (int4 per sub: keys kt*64+sub*16+quad*4+r) + row sums
        #pragma unroll
        for (int sub = 0; sub < 4; ++sub) {
            const int4 m4 = *(const int4*)&mrow[kt * 64 + sub * 16 + quad * 4];
            const float md0 = m4.x ? 0.f : -3.0e38f;
            const float md1 = m4.y ? 0.f : -3.0e38f;
            const float md2 = m4.z ? 0.f : -3.0e38f;
            const float md3 = m4.w ? 0.f : -3.0e38f;
            const float p0 = __builtin_amdgcn_exp2f(sf[sub][0] * SC + md0);
            const float p1 = __builtin_amdgcn_exp2f(sf[sub][1] * SC + md1);
            const float p2 = __builtin_amdgcn_exp2f(sf[sub][2] * SC + md2);
            const float p3 = __builtin_amdgcn_exp2f(sf[sub][3] * SC + md3);
            sf[sub][0] = p0; sf[sub][1] = p1; sf[sub][2] = p2; sf[sub][3] = p3;
            lsum += (p0 + p1) + (p2 + p3);
        }
        // P -> Pl[q][key]: packed b64 writes, XOR part-swizzle
        #pragma unroll
        for (int sub = 0; sub < 4; ++sub) {
            bf16x4 pk = {(bf16)sf[sub][0], (bf16)sf[sub][1],
                         (bf16)sf[sub][2], (bf16)sf[sub][3]};
            const int slot = (sub * 2 + (quad >> 1)) ^ (l16 & 7);
            *(bf16x4*)&Pl[wave][l16 * 64 + slot * 8 + (quad & 1) * 4] = pk;
        }
        bf16x8 af[2];
        #pragma unroll
        for (int hh = 0; hh < 2; ++hh) {
            const int slot = (hh * 4 + quad) ^ (l16 & 7);
            af[hh] = *(const bf16x8*)&Pl[wave][l16 * 64 + slot * 8];
        }
        // O += P V (A = P rows, B = V^T rows)
        __builtin_amdgcn_s_setprio(1);
        #pragma unroll
        for (int dsub = 0; dsub < 4; ++dsub) {
            const int rowd = dsub * 16 + l16;
            bf16x8 v0 = *(const bf16x8*)(Vt[cur] + rowd * 64 + ((quad ^ (rowd & 7)) << 3));
            bf16x8 v1 = *(const bf16x8*)(Vt[cur] + rowd * 64 + (((quad + 4) ^ (rowd & 7)) << 3));
            o[dsub] = __builtin_amdgcn_mfma_f32_16x16x32_bf16(af[0], v0, o[dsub], 0, 0, 0);
            o[dsub] = __builtin_amdgcn_mfma_f32_16x16x32_bf16(af[1], v1, o[dsub], 0, 0, 0);
        }
        __builtin_amdgcn_s_setprio(0);
    }

    // reduce row sums (lane l16 = q) across quad groups; broadcast; store
    float lr = lsum;
    lr += __shfl_xor(lr, 16, 64);
    lr += __shfl_xor(lr, 32, 64);
    const float inv = 1.f / lr;
    float linv[4];
    #pragma unroll
    for (int r = 0; r < 4; ++r) linv[r] = __shfl(inv, quad * 4 + r, 64);
    for (int dsub = 0; dsub < 4; ++dsub) {
        for (int r = 0; r < 4; ++r) {
            const int q = qblk * 64 + wave * 16 + quad * 4 + r;
            const int col = hd * 64 + dsub * 16 + l16;
            Oa[((size_t)(b * NQ + q)) * DIM + col] = (bf16)(o[dsub][r] * linv[r]);
        }
    }
}

// ---------------------------------------------------------------------------
// ffn_gemm: 128x128 tile, BK=64, XOR-swizzled staging, m-minor mapping,
// K-loop double-buffer (computed LDS pointers — see proj note).
// Yb (bf16) = Oa + relu(Oa @ Wo^T + bo). 256 blocks.
// ---------------------------------------------------------------------------
__global__ __launch_bounds__(256) void ffn_gemm(
    const bf16* __restrict__ Oa, const bf16* __restrict__ W,
    const float* __restrict__ bias, bf16* __restrict__ Yb)
{
    __shared__ __attribute__((aligned(16))) bf16 sh[32768];  // 64 KB: A0|A1|B0|B1
    const int t = threadIdx.x;
    const int wave = t >> 6, lane = t & 63, quad = lane >> 4, l16 = lane & 15;
    const int wr = wave >> 1, wc = wave & 1;
    const int m0 = (blockIdx.x & 63) * 128, n0 = (blockIdx.x >> 6) * 128;

    const int r1 = t >> 3, s1 = t & 7;
    const int p1 = s1 ^ (r1 & 7);
    const bf16* aSrc = Oa + (size_t)(m0 + r1) * DIM + p1 * 8;
    const bf16* wSrc = W  + (size_t)(n0 + r1) * DIM + p1 * 8;

    floatx4 acc[4][4];
    for (int i = 0; i < 4; ++i)
        for (int j = 0; j < 4; ++j) acc[i][j] = (floatx4){0.f, 0.f, 0.f, 0.f};

    #pragma unroll
    for (int j = 0; j < 4; ++j) {
        async16(aSrc + (size_t)j * 32 * DIM, sh + (t + j * 256) * 8);
        async16(wSrc + (size_t)j * 32 * DIM, sh + 16384 + (t + j * 256) * 8);
    }

    for (int kt = 0; kt < 8; ++kt) {
        __syncthreads();
        const int cur = kt & 1;
        bf16* Acur = sh + cur * 8192;
        bf16* Bcur = sh + 16384 + cur * 8192;
        if (kt < 7) {
            bf16* Anxt = sh + (1 - cur) * 8192;
            bf16* Bnxt = sh + 16384 + (1 - cur) * 8192;
            const int ko = (kt + 1) * 64;
            #pragma unroll
            for (int j = 0; j < 4; ++j) {
                async16(aSrc + ko + (size_t)j * 32 * DIM, Anxt + (t + j * 256) * 8);
                async16(wSrc + ko + (size_t)j * 32 * DIM, Bnxt + (t + j * 256) * 8);
            }
        }
        #pragma unroll
        for (int ks = 0; ks < 2; ++ks) {
            bf16x8 af[4], bfr[4];
            #pragma unroll
            for (int mi = 0; mi < 4; ++mi) {
                const int row = wr * 64 + mi * 16 + l16;
                af[mi] = *(const bf16x8*)(Acur + row * 64 + (((ks * 4 + quad) ^ (row & 7)) << 3));
            }
            #pragma unroll
            for (int ni = 0; ni < 4; ++ni) {
                const int row = wc * 64 + ni * 16 + l16;
                bfr[ni] = *(const bf16x8*)(Bcur + row * 64 + (((ks * 4 + quad) ^ (row & 7)) << 3));
            }
            #pragma unroll
            for (int mi = 0; mi < 4; ++mi)
                #pragma unroll
                for (int ni = 0; ni < 4; ++ni)
                    acc[mi][ni] = __builtin_amdgcn_mfma_f32_16x16x32_bf16(
                        af[mi], bfr[ni], acc[mi][ni], 0, 0, 0);
        }
    }

    for (int ni = 0; ni < 4; ++ni) {
        const int n = n0 + wc * 64 + ni * 16 + l16;
        const float bb = bias[n];
        for (int mi = 0; mi < 4; ++mi) {
            for (int r = 0; r < 4; ++r) {
                const int m = m0 + wr * 64 + mi * 16 + quad * 4 + r;
                const float ov = (float)Oa[(size_t)m * DIM + n];
                Yb[(size_t)m * DIM + n] = (bf16)(ov + fmaxf(acc[mi][ni][r] + bb, 0.f));
            }
        }
    }
}

// ---------------------------------------------------------------------------
// ln: LayerNorm over last dim (512). One wave per row; bf16 in, fp32 out.
// Each lane owns 8 contiguous cols (one bf16x8 load).
// ---------------------------------------------------------------------------
__global__ __launch_bounds__(256) void ln_kernel(
    const bf16* __restrict__ Y, const float* __restrict__ gamma,
    const float* __restrict__ beta, float* __restrict__ out)
{
    const int row  = blockIdx.x * 4 + (threadIdx.x >> 6);
    const int lane = threadIdx.x & 63;
    bf16x8 v = *(const bf16x8*)(Y + (size_t)row * DIM + lane * 8);
    float f[8];
    float s = 0.f, sq = 0.f;
    #pragma unroll
    for (int j = 0; j < 8; ++j) {
        f[j] = (float)v[j];
        s += f[j];
        sq += f[j] * f[j];
    }
    for (int mk = 32; mk >= 1; mk >>= 1) {
        s  += __shfl_xor(s,  mk, 64);
        sq += __shfl_xor(sq, mk, 64);
    }
    const float mu  = s * (1.f / 512.f);
    const float var = sq * (1.f / 512.f) - mu * mu;
    const float inv = rsqrtf(var + 1e-5f);
    float4 g1 = ((const float4*)gamma)[lane * 2];
    float4 g2 = ((const float4*)gamma)[lane * 2 + 1];
    float4 b1 = ((const float4*)beta)[lane * 2];
    float4 b2 = ((const float4*)beta)[lane * 2 + 1];
    float4 o1, o2;
    o1.x = (f[0] - mu) * inv * g1.x + b1.x;
    o1.y = (f[1] - mu) * inv * g1.y + b1.y;
    o1.z = (f[2] - mu) * inv * g1.z + b1.z;
    o1.w = (f[3] - mu) * inv * g1.w + b1.w;
    o2.x = (f[4] - mu) * inv * g2.x + b2.x;
    o2.y = (f[5] - mu) * inv * g2.y + b2.y;
    o2.z = (f[6] - mu) * inv * g2.z + b2.z;
    o2.w = (f[7] - mu) * inv * g2.w + b2.w;
    float* orow = out + (size_t)row * DIM;
    ((float4*)orow)[lane * 2]     = o1;
    ((float4*)orow)[lane * 2 + 1] = o2;
}

// ---------------------------------------------------------------------------
extern "C" void kernel_launch(void* const* d_in, const int* in_sizes, int n_in,
                              void* d_out, int out_size, void* d_ws, size_t ws_size,
                              hipStream_t stream) {
    const float* Q  = (const float*)d_in[0];
    const float* K  = (const float*)d_in[1];
    const int*   mask = (const int*)d_in[2];
    const float* Wq = (const float*)d_in[3];
    const float* bq = (const float*)d_in[4];
    const float* Wk = (const float*)d_in[5];
    const float* bk = (const float*)d_in[6];
    const float* Wv = (const float*)d_in[7];
    const float* bv = (const float*)d_in[8];
    const float* Wo = (const float*)d_in[9];
    const float* bo = (const float*)d_in[10];
    const float* gamma = (const float*)d_in[11];
    const float* beta  = (const float*)d_in[12];

    char* ws = (char*)d_ws;
    bf16* Wt  = (bf16*)(ws);                   // 2 MB (4 x 512x512 bf16, transposed)
    bf16* Qb  = (bf16*)(ws + 2097152);         // 8 MB
    bf16* Kb  = (bf16*)(ws + 10485760);        // 8 MB
    bf16* Qp  = (bf16*)(ws + 18874368);        // 8 MB  [b,h,q,64]
    bf16* Kp  = (bf16*)(ws + 27262976);        // 8 MB  [b,h,k,64]
    bf16* Vpt = (bf16*)(ws + 35651584);        // 8 MB  [b,h,d,1024]
    bf16* Oa  = (bf16*)(ws + 44040192);        // 8 MB  [b,q,512]
    bf16* Yb  = (bf16*)(ws + 52428800);        // 8 MB  [b,q,512] bf16
    float* out = (float*)d_out;

    prep_fused<<<4352, 256, 0, stream>>>(Q, K, Wq, Wk, Wv, Wo, Qb, Kb, Wt);
    proj_fused<<<768, 256, 0, stream>>>(Qb, Kb, Wt, bq, bk, bv, Qp, Kp, Vpt);
    attn_kernel<<<1024, 256, 0, stream>>>(Qp, Kp, Vpt, mask, Oa);
    ffn_gemm<<<256, 256, 0, stream>>>(Oa, Wt + 3 * 262144, bo, Yb);
    ln_kernel<<<2048, 256, 0, stream>>>(Yb, gamma, beta, out);
}

// Round 3
// 169.027 us; speedup vs baseline: 1.0496x; 1.0082x over previous
//
#include <hip/hip_runtime.h>

typedef __bf16 bf16;
typedef bf16 bf16x4 __attribute__((ext_vector_type(4)));
typedef bf16 bf16x8 __attribute__((ext_vector_type(8)));
typedef float floatx4 __attribute__((ext_vector_type(4)));

#define NB 8
#define NQ 1024
#define NK 1024
#define DIM 512
#define NH 8
#define DH 64

// async global->LDS, 16B per lane. LDS dest must be wave-uniform base + lane*16B.
__device__ __forceinline__ void async16(const void* g, void* l) {
    __builtin_amdgcn_global_load_lds(
        (const __attribute__((address_space(1))) unsigned int*)(unsigned long long)(g),
        (__attribute__((address_space(3))) unsigned int*)(unsigned long long)(l),
        16, 0, 0);
}

// ---------------------------------------------------------------------------
// prep_fused: blocks [0,4096): cast Q,K fp32->bf16 (float4 vectorized);
//             blocks [4096,4352): Wt[w][n][k] = (bf16)W[k][n], LDS 64x64 tiles.
// ---------------------------------------------------------------------------
__global__ __launch_bounds__(256) void prep_fused(
    const float* __restrict__ Q, const float* __restrict__ K,
    const float* __restrict__ Wq, const float* __restrict__ Wk,
    const float* __restrict__ Wv, const float* __restrict__ Wo,
    bf16* __restrict__ Qb, bf16* __restrict__ Kb, bf16* __restrict__ Wt)
{
    __shared__ bf16 Tl[64][68];
    const int bid = blockIdx.x;
    if (bid < 4096) {
        const int i = bid * 256 + threadIdx.x;   // float4 index
        float4 a = ((const float4*)Q)[i];
        float4 c = ((const float4*)K)[i];
        bf16x4 qa = {(bf16)a.x, (bf16)a.y, (bf16)a.z, (bf16)a.w};
        bf16x4 ka = {(bf16)c.x, (bf16)c.y, (bf16)c.z, (bf16)c.w};
        *(bf16x4*)(Qb + (size_t)i * 4) = qa;
        *(bf16x4*)(Kb + (size_t)i * 4) = ka;
    } else {
        const int bid2 = bid - 4096;
        const int w = bid2 >> 6;
        const int bx = bid2 & 7, by = (bid2 >> 3) & 7;
        const float* W = (w == 0) ? Wq : (w == 1) ? Wk : (w == 2) ? Wv : Wo;
        bf16* out = Wt + (size_t)w * DIM * DIM;
        const int k0 = bx * 64, n0 = by * 64;
        const int tx = threadIdx.x & 15, ty = threadIdx.x >> 4;
        for (int pass = 0; pass < 4; ++pass) {
            int k = ty + pass * 16;
            float4 v = *(const float4*)&W[(size_t)(k0 + k) * DIM + n0 + tx * 4];
            Tl[tx * 4 + 0][k] = (bf16)v.x;
            Tl[tx * 4 + 1][k] = (bf16)v.y;
            Tl[tx * 4 + 2][k] = (bf16)v.z;
            Tl[tx * 4 + 3][k] = (bf16)v.w;
        }
        __syncthreads();
        for (int pass = 0; pass < 4; ++pass) {
            int n = ty + pass * 16;
            bf16x4 ov = *(const bf16x4*)&Tl[n][tx * 4];
            *(bf16x4*)&out[(size_t)(n0 + n) * DIM + k0 + tx * 4] = ov;
        }
    }
}

// ---------------------------------------------------------------------------
// proj_fused: 128x128 tiles, BK=64, XOR-swizzled async staging, m-minor
// block mapping (XCD L2 locality). K-loop LDS double-buffer (attn-style).
// NOTE: LDS buffer selection must be a computed pointer (sh + cur*off) —
// a local array of LDS pointers fails gfx950 codegen (addrspacecast init).
// blocks [0,256):   Q proj -> Qp head layout [b,h,q,64], PRE-SCALED by
//                   SC = 1/(sqrt(64)*0.1)*log2(e) so attn S is exp2-ready.
// blocks [256,768): KV proj: n<512 -> Kp head layout; n>=512 -> Vpt
//                   [b,h,d,1024] via in-LDS transpose (coalesced stores).
// ---------------------------------------------------------------------------
__global__ __launch_bounds__(256) void proj_fused(
    const bf16* __restrict__ Qb, const bf16* __restrict__ Kb,
    const bf16* __restrict__ Wt,
    const float* __restrict__ bq, const float* __restrict__ bk,
    const float* __restrict__ bv,
    bf16* __restrict__ Qp, bf16* __restrict__ Kp, bf16* __restrict__ Vpt)
{
    __shared__ __attribute__((aligned(16))) bf16 sh[32768];  // 64 KB: A0|A1|B0|B1
    const int t = threadIdx.x;
    const int wave = t >> 6, lane = t & 63, quad = lane >> 4, l16 = lane & 15;
    const int wr = wave >> 1, wc = wave & 1;
    const int bid = blockIdx.x;
    const bool isQ = bid < 256;
    const bf16* A; const bf16* W; int m0, n0;
    if (isQ) { A = Qb; W = Wt;             m0 = (bid & 63) * 128;  n0 = (bid >> 6) * 128; }
    else     { int b2 = bid - 256;
               A = Kb; W = Wt + 512 * DIM; m0 = (b2 & 63) * 128;   n0 = (b2 >> 6) * 128; }

    const int r1 = t >> 3, s1 = t & 7;
    const int p1 = s1 ^ (r1 & 7);          // rows r1+32j keep row&7
    const bf16* aSrc = A + (size_t)(m0 + r1) * DIM + p1 * 8;
    const bf16* wSrc = W + (size_t)(n0 + r1) * DIM + p1 * 8;

    floatx4 acc[4][4];
    for (int i = 0; i < 4; ++i)
        for (int j = 0; j < 4; ++j) acc[i][j] = (floatx4){0.f, 0.f, 0.f, 0.f};

    // prologue: issue kt=0 into buf 0 (A at sh+0, B at sh+16384)
    #pragma unroll
    for (int j = 0; j < 4; ++j) {
        async16(aSrc + (size_t)j * 32 * DIM, sh + (t + j * 256) * 8);
        async16(wSrc + (size_t)j * 32 * DIM, sh + 16384 + (t + j * 256) * 8);
    }

    for (int kt = 0; kt < 8; ++kt) {
        __syncthreads();   // tile kt loads done; all waves done with other buf
        const int cur = kt & 1;
        bf16* Acur = sh + cur * 8192;
        bf16* Bcur = sh + 16384 + cur * 8192;
        if (kt < 7) {
            bf16* Anxt = sh + (1 - cur) * 8192;
            bf16* Bnxt = sh + 16384 + (1 - cur) * 8192;
            const int ko = (kt + 1) * 64;
            #pragma unroll
            for (int j = 0; j < 4; ++j) {
                async16(aSrc + ko + (size_t)j * 32 * DIM, Anxt + (t + j * 256) * 8);
                async16(wSrc + ko + (size_t)j * 32 * DIM, Bnxt + (t + j * 256) * 8);
            }
        }
        #pragma unroll
        for (int ks = 0; ks < 2; ++ks) {
            bf16x8 af[4], bfr[4];
            #pragma unroll
            for (int mi = 0; mi < 4; ++mi) {
                const int row = wr * 64 + mi * 16 + l16;
                af[mi] = *(const bf16x8*)(Acur + row * 64 + (((ks * 4 + quad) ^ (row & 7)) << 3));
            }
            #pragma unroll
            for (int ni = 0; ni < 4; ++ni) {
                const int row = wc * 64 + ni * 16 + l16;
                bfr[ni] = *(const bf16x8*)(Bcur + row * 64 + (((ks * 4 + quad) ^ (row & 7)) << 3));
            }
            #pragma unroll
            for (int mi = 0; mi < 4; ++mi)
                #pragma unroll
                for (int ni = 0; ni < 4; ++ni)
                    acc[mi][ni] = __builtin_amdgcn_mfma_f32_16x16x32_bf16(
                        af[mi], bfr[ni], acc[mi][ni], 0, 0, 0);
        }
    }

    const bool isV = (!isQ) && (n0 >= 512);
    if (!isV) {
        bf16* out = isQ ? Qp : Kp;
        const float* bias = isQ ? bq : bk;
        const float qscale = isQ ? 1.8033688f : 1.0f;   // SC folded into Qp
        for (int ni = 0; ni < 4; ++ni) {
            const int n = n0 + wc * 64 + ni * 16 + l16;
            const float bb = bias[n];
            const int hd = n >> 6, d = n & 63;
            for (int mi = 0; mi < 4; ++mi) {
                for (int r = 0; r < 4; ++r) {
                    const int m = m0 + wr * 64 + mi * 16 + quad * 4 + r;
                    const int b = m >> 10, q = m & 1023;
                    out[((size_t)(b * 8 + hd) * 1024 + q) * 64 + d] =
                        (bf16)((acc[mi][ni][r] + bb) * qscale);
                }
            }
        }
    } else {
        // dump tile (+bias) to LDS as Tb[n][m] (first 32 KB of sh) with
        // chunk-XOR swizzle, then store coalesced rows of Vpt [b,h,d,1024]
        __syncthreads();
        for (int ni = 0; ni < 4; ++ni) {
            const int n = wc * 64 + ni * 16 + l16;           // local n
            const float bb = bv[n0 + n - 512];
            for (int mi = 0; mi < 4; ++mi) {
                const int mb = wr * 64 + mi * 16 + quad * 4;  // local m base (r=0..3)
                const int slot = ((mb >> 3) ^ (n & 15));
                bf16x4 pk = {(bf16)(acc[mi][ni][0] + bb), (bf16)(acc[mi][ni][1] + bb),
                             (bf16)(acc[mi][ni][2] + bb), (bf16)(acc[mi][ni][3] + bb)};
                *(bf16x4*)(sh + n * 128 + slot * 8 + (mb & 7)) = pk;
            }
        }
        __syncthreads();
        const int n = t >> 1, hf = t & 1;
        const int nv = n0 + n - 512, hd = nv >> 6, d = nv & 63;
        const int b = m0 >> 10, qb = m0 & 1023;
        bf16* dst = Vpt + ((size_t)(b * 8 + hd) * 64 + d) * 1024 + qb + hf * 64;
        #pragma unroll
        for (int j = 0; j < 8; ++j) {
            const int ch = hf * 8 + j;
            const int slot = ch ^ (n & 15);
            bf16x8 v8 = *(const bf16x8*)(sh + n * 128 + slot * 8);
            *(bf16x8*)(dst + j * 8) = v8;
        }
    }
}

// ---------------------------------------------------------------------------
// attn: flash attention per (b,h). 1024 blocks x 4 waves, 64 q/block,
// 16 q/wave (4096 waves, LDS 40KB -> 4 blocks/CU). 16x16x32 MFMA, S^T
// trick (A=K, B=Q). Q pre-scaled in proj -> P = exp2(S) directly.
// Mask: 1-load + __all ballot fast path (uniform branch).
// Denominator: mfma(P, ones) row-sum on the matrix pipe (no VALU adds,
// no epilogue shuffles). K/V LDS double-buffer via global_load_lds.
// ---------------------------------------------------------------------------
__global__ __launch_bounds__(256) void attn_kernel(
    const bf16* __restrict__ Qp, const bf16* __restrict__ Kp,
    const bf16* __restrict__ Vpt, const int* __restrict__ mask,
    bf16* __restrict__ Oa)
{
    const int bh = blockIdx.x & 63, qblk = blockIdx.x >> 6;  // qblk 0..15
    const int b = bh >> 3, hd = bh & 7;
    const int t = threadIdx.x;
    const int wave = t >> 6, lane = t & 63, quad = lane >> 4, l16 = lane & 15;

    __shared__ __attribute__((aligned(16))) bf16 Kt[2][64 * 64];
    __shared__ __attribute__((aligned(16))) bf16 Vt[2][64 * 64];
    __shared__ __attribute__((aligned(16))) bf16 Pl[4][16 * 64];

    const bf16* Qbase = Qp + ((size_t)bh * NQ + qblk * 64 + wave * 16) * DH;
    const bf16* Kbase = Kp + (size_t)bh * NK * DH;
    const bf16* Vbase = Vpt + (size_t)bh * DH * NK;
    const int* mrow = mask + b * NK;

    // Q B-frags (col=q=l16, k = hh*32 + quad*8 + j), kept in regs
    bf16x8 qf[2];
    #pragma unroll
    for (int hh = 0; hh < 2; ++hh)
        qf[hh] = *(const bf16x8*)(Qbase + (size_t)l16 * DH + hh * 32 + quad * 8);

    // all-ones B-frag for the denominator row-sum MFMA
    bf16x8 onesv;
    #pragma unroll
    for (int j = 0; j < 8; ++j) onesv[j] = (bf16)1.0f;

    floatx4 o[4];
    floatx4 osum = (floatx4){0.f, 0.f, 0.f, 0.f};
    #pragma unroll
    for (int i = 0; i < 4; ++i) o[i] = (floatx4){0.f, 0.f, 0.f, 0.f};

    const int r1 = t >> 3, s1 = t & 7;
    const int p1 = s1 ^ (r1 & 7);          // (r1+32)&7 == r1&7
    const bf16* kSrc = Kbase + r1 * 64 + p1 * 8;            // + kt*4096
    const bf16* vSrc = Vbase + (size_t)r1 * 1024 + p1 * 8;  // + kt*64

    // prologue: issue tile 0 into buf 0
    async16(kSrc, Kt[0] + t * 8);
    async16(kSrc + 32 * 64, Kt[0] + (t + 256) * 8);
    async16(vSrc, Vt[0] + t * 8);
    async16(vSrc + (size_t)32 * 1024, Vt[0] + (t + 256) * 8);

    for (int kt = 0; kt < NK / 64; ++kt) {
        __syncthreads();   // tile kt loads complete; all waves done with other buf
        const int cur = kt & 1;
        if (kt < NK / 64 - 1) {
            const int nxt = 1 - cur;
            async16(kSrc + (kt + 1) * 4096, Kt[nxt] + t * 8);
            async16(kSrc + (kt + 1) * 4096 + 32 * 64, Kt[nxt] + (t + 256) * 8);
            async16(vSrc + (kt + 1) * 64, Vt[nxt] + t * 8);
            async16(vSrc + (kt + 1) * 64 + (size_t)32 * 1024, Vt[nxt] + (t + 256) * 8);
        }

        // K A-frags (lane = key-within-subtile), conflict-free quad-spread
        bf16x8 kb[4][2];
        #pragma unroll
        for (int sub = 0; sub < 4; ++sub) {
            const int rowk = sub * 16 + l16;
            kb[sub][0] = *(const bf16x8*)(Kt[cur] + rowk * 64 + ((quad ^ (rowk & 7)) << 3));
            kb[sub][1] = *(const bf16x8*)(Kt[cur] + rowk * 64 + (((quad + 4) ^ (rowk & 7)) << 3));
        }
        // S^T = K Q^T: C col = q (l16), row = key-within-sub (quad*4+r)
        floatx4 sf[4];
        __builtin_amdgcn_s_setprio(1);
        #pragma unroll
        for (int sub = 0; sub < 4; ++sub) {
            floatx4 s = {0.f, 0.f, 0.f, 0.f};
            s = __builtin_amdgcn_mfma_f32_16x16x32_bf16(kb[sub][0], qf[0], s, 0, 0, 0);
            s = __builtin_amdgcn_mfma_f32_16x16x32_bf16(kb[sub][1], qf[1], s, 0, 0, 0);
            sf[sub] = s;
        }
        __builtin_amdgcn_s_setprio(0);

        // mask: wave-uniform fast path (1 dword/lane + ballot per 64-key tile)
        const int mv = mrow[kt * 64 + lane];
        if (!__all(mv != 0)) {
            #pragma unroll
            for (int sub = 0; sub < 4; ++sub) {
                const int4 m4 = *(const int4*)&mrow[kt * 64 + sub * 16 + quad * 4];
                if (!m4.x) sf[sub][0] = -3.0e38f;
                if (!m4.y) sf[sub][1] = -3.0e38f;
                if (!m4.z) sf[sub][2] = -3.0e38f;
                if (!m4.w) sf[sub][3] = -3.0e38f;
            }
        }
        // P = exp2(S') (scale pre-folded into Qp)
        #pragma unroll
        for (int sub = 0; sub < 4; ++sub) {
            sf[sub][0] = __builtin_amdgcn_exp2f(sf[sub][0]);
            sf[sub][1] = __builtin_amdgcn_exp2f(sf[sub][1]);
            sf[sub][2] = __builtin_amdgcn_exp2f(sf[sub][2]);
            sf[sub][3] = __builtin_amdgcn_exp2f(sf[sub][3]);
        }
        // P -> Pl[q][key]: packed b64 writes, XOR part-swizzle
        #pragma unroll
        for (int sub = 0; sub < 4; ++sub) {
            bf16x4 pk = {(bf16)sf[sub][0], (bf16)sf[sub][1],
                         (bf16)sf[sub][2], (bf16)sf[sub][3]};
            const int slot = (sub * 2 + (quad >> 1)) ^ (l16 & 7);
            *(bf16x4*)&Pl[wave][l16 * 64 + slot * 8 + (quad & 1) * 4] = pk;
        }
        bf16x8 af[2];
        #pragma unroll
        for (int hh = 0; hh < 2; ++hh) {
            const int slot = (hh * 4 + quad) ^ (l16 & 7);
            af[hh] = *(const bf16x8*)&Pl[wave][l16 * 64 + slot * 8];
        }
        // O += P V; denominator via mfma(P, ones) on the same pipe
        __builtin_amdgcn_s_setprio(1);
        osum = __builtin_amdgcn_mfma_f32_16x16x32_bf16(af[0], onesv, osum, 0, 0, 0);
        osum = __builtin_amdgcn_mfma_f32_16x16x32_bf16(af[1], onesv, osum, 0, 0, 0);
        #pragma unroll
        for (int dsub = 0; dsub < 4; ++dsub) {
            const int rowd = dsub * 16 + l16;
            bf16x8 v0 = *(const bf16x8*)(Vt[cur] + rowd * 64 + ((quad ^ (rowd & 7)) << 3));
            bf16x8 v1 = *(const bf16x8*)(Vt[cur] + rowd * 64 + (((quad + 4) ^ (rowd & 7)) << 3));
            o[dsub] = __builtin_amdgcn_mfma_f32_16x16x32_bf16(af[0], v0, o[dsub], 0, 0, 0);
            o[dsub] = __builtin_amdgcn_mfma_f32_16x16x32_bf16(af[1], v1, o[dsub], 0, 0, 0);
        }
        __builtin_amdgcn_s_setprio(0);
    }

    // osum[r] = full denominator for q = quad*4 + r (replicated over l16)
    float linv[4];
    #pragma unroll
    for (int r = 0; r < 4; ++r) linv[r] = 1.f / osum[r];
    for (int dsub = 0; dsub < 4; ++dsub) {
        for (int r = 0; r < 4; ++r) {
            const int q = qblk * 64 + wave * 16 + quad * 4 + r;
            const int col = hd * 64 + dsub * 16 + l16;
            Oa[((size_t)(b * NQ + q)) * DIM + col] = (bf16)(o[dsub][r] * linv[r]);
        }
    }
}

// ---------------------------------------------------------------------------
// ffn_gemm: 128x128 tile, BK=64, XOR-swizzled staging, m-minor mapping,
// K-loop double-buffer (computed LDS pointers — see proj note).
// Yb (bf16) = Oa + relu(Oa @ Wo^T + bo). 256 blocks.
// ---------------------------------------------------------------------------
__global__ __launch_bounds__(256) void ffn_gemm(
    const bf16* __restrict__ Oa, const bf16* __restrict__ W,
    const float* __restrict__ bias, bf16* __restrict__ Yb)
{
    __shared__ __attribute__((aligned(16))) bf16 sh[32768];  // 64 KB: A0|A1|B0|B1
    const int t = threadIdx.x;
    const int wave = t >> 6, lane = t & 63, quad = lane >> 4, l16 = lane & 15;
    const int wr = wave >> 1, wc = wave & 1;
    const int m0 = (blockIdx.x & 63) * 128, n0 = (blockIdx.x >> 6) * 128;

    const int r1 = t >> 3, s1 = t & 7;
    const int p1 = s1 ^ (r1 & 7);
    const bf16* aSrc = Oa + (size_t)(m0 + r1) * DIM + p1 * 8;
    const bf16* wSrc = W  + (size_t)(n0 + r1) * DIM + p1 * 8;

    floatx4 acc[4][4];
    for (int i = 0; i < 4; ++i)
        for (int j = 0; j < 4; ++j) acc[i][j] = (floatx4){0.f, 0.f, 0.f, 0.f};

    #pragma unroll
    for (int j = 0; j < 4; ++j) {
        async16(aSrc + (size_t)j * 32 * DIM, sh + (t + j * 256) * 8);
        async16(wSrc + (size_t)j * 32 * DIM, sh + 16384 + (t + j * 256) * 8);
    }

    for (int kt = 0; kt < 8; ++kt) {
        __syncthreads();
        const int cur = kt & 1;
        bf16* Acur = sh + cur * 8192;
        bf16* Bcur = sh + 16384 + cur * 8192;
        if (kt < 7) {
            bf16* Anxt = sh + (1 - cur) * 8192;
            bf16* Bnxt = sh + 16384 + (1 - cur) * 8192;
            const int ko = (kt + 1) * 64;
            #pragma unroll
            for (int j = 0; j < 4; ++j) {
                async16(aSrc + ko + (size_t)j * 32 * DIM, Anxt + (t + j * 256) * 8);
                async16(wSrc + ko + (size_t)j * 32 * DIM, Bnxt + (t + j * 256) * 8);
            }
        }
        #pragma unroll
        for (int ks = 0; ks < 2; ++ks) {
            bf16x8 af[4], bfr[4];
            #pragma unroll
            for (int mi = 0; mi < 4; ++mi) {
                const int row = wr * 64 + mi * 16 + l16;
                af[mi] = *(const bf16x8*)(Acur + row * 64 + (((ks * 4 + quad) ^ (row & 7)) << 3));
            }
            #pragma unroll
            for (int ni = 0; ni < 4; ++ni) {
                const int row = wc * 64 + ni * 16 + l16;
                bfr[ni] = *(const bf16x8*)(Bcur + row * 64 + (((ks * 4 + quad) ^ (row & 7)) << 3));
            }
            #pragma unroll
            for (int mi = 0; mi < 4; ++mi)
                #pragma unroll
                for (int ni = 0; ni < 4; ++ni)
                    acc[mi][ni] = __builtin_amdgcn_mfma_f32_16x16x32_bf16(
                        af[mi], bfr[ni], acc[mi][ni], 0, 0, 0);
        }
    }

    for (int ni = 0; ni < 4; ++ni) {
        const int n = n0 + wc * 64 + ni * 16 + l16;
        const float bb = bias[n];
        for (int mi = 0; mi < 4; ++mi) {
            for (int r = 0; r < 4; ++r) {
                const int m = m0 + wr * 64 + mi * 16 + quad * 4 + r;
                const float ov = (float)Oa[(size_t)m * DIM + n];
                Yb[(size_t)m * DIM + n] = (bf16)(ov + fmaxf(acc[mi][ni][r] + bb, 0.f));
            }
        }
    }
}

// ---------------------------------------------------------------------------
// ln: LayerNorm over last dim (512). One wave per row; bf16 in, fp32 out.
// Each lane owns 8 contiguous cols (one bf16x8 load).
// ---------------------------------------------------------------------------
__global__ __launch_bounds__(256) void ln_kernel(
    const bf16* __restrict__ Y, const float* __restrict__ gamma,
    const float* __restrict__ beta, float* __restrict__ out)
{
    const int row  = blockIdx.x * 4 + (threadIdx.x >> 6);
    const int lane = threadIdx.x & 63;
    bf16x8 v = *(const bf16x8*)(Y + (size_t)row * DIM + lane * 8);
    float f[8];
    float s = 0.f, sq = 0.f;
    #pragma unroll
    for (int j = 0; j < 8; ++j) {
        f[j] = (float)v[j];
        s += f[j];
        sq += f[j] * f[j];
    }
    for (int mk = 32; mk >= 1; mk >>= 1) {
        s  += __shfl_xor(s,  mk, 64);
        sq += __shfl_xor(sq, mk, 64);
    }
    const float mu  = s * (1.f / 512.f);
    const float var = sq * (1.f / 512.f) - mu * mu;
    const float inv = rsqrtf(var + 1e-5f);
    float4 g1 = ((const float4*)gamma)[lane * 2];
    float4 g2 = ((const float4*)gamma)[lane * 2 + 1];
    float4 b1 = ((const float4*)beta)[lane * 2];
    float4 b2 = ((const float4*)beta)[lane * 2 + 1];
    float4 o1, o2;
    o1.x = (f[0] - mu) * inv * g1.x + b1.x;
    o1.y = (f[1] - mu) * inv * g1.y + b1.y;
    o1.z = (f[2] - mu) * inv * g1.z + b1.z;
    o1.w = (f[3] - mu) * inv * g1.w + b1.w;
    o2.x = (f[4] - mu) * inv * g2.x + b2.x;
    o2.y = (f[5] - mu) * inv * g2.y + b2.y;
    o2.z = (f[6] - mu) * inv * g2.z + b2.z;
    o2.w = (f[7] - mu) * inv * g2.w + b2.w;
    float* orow = out + (size_t)row * DIM;
    ((float4*)orow)[lane * 2]     = o1;
    ((float4*)orow)[lane * 2 + 1] = o2;
}

// ---------------------------------------------------------------------------
extern "C" void kernel_launch(void* const* d_in, const int* in_sizes, int n_in,
                              void* d_out, int out_size, void* d_ws, size_t ws_size,
                              hipStream_t stream) {
    const float* Q  = (const float*)d_in[0];
    const float* K  = (const float*)d_in[1];
    const int*   mask = (const int*)d_in[2];
    const float* Wq = (const float*)d_in[3];
    const float* bq = (const float*)d_in[4];
    const float* Wk = (const float*)d_in[5];
    const float* bk = (const float*)d_in[6];
    const float* Wv = (const float*)d_in[7];
    const float* bv = (const float*)d_in[8];
    const float* Wo = (const float*)d_in[9];
    const float* bo = (const float*)d_in[10];
    const float* gamma = (const float*)d_in[11];
    const float* beta  = (const float*)d_in[12];

    char* ws = (char*)d_ws;
    bf16* Wt  = (bf16*)(ws);                   // 2 MB (4 x 512x512 bf16, transposed)
    bf16* Qb  = (bf16*)(ws + 2097152);         // 8 MB
    bf16* Kb  = (bf16*)(ws + 10485760);        // 8 MB
    bf16* Qp  = (bf16*)(ws + 18874368);        // 8 MB  [b,h,q,64] (pre-scaled)
    bf16* Kp  = (bf16*)(ws + 27262976);        // 8 MB  [b,h,k,64]
    bf16* Vpt = (bf16*)(ws + 35651584);        // 8 MB  [b,h,d,1024]
    bf16* Oa  = (bf16*)(ws + 44040192);        // 8 MB  [b,q,512]
    bf16* Yb  = (bf16*)(ws + 52428800);        // 8 MB  [b,q,512] bf16
    float* out = (float*)d_out;

    prep_fused<<<4352, 256, 0, stream>>>(Q, K, Wq, Wk, Wv, Wo, Qb, Kb, Wt);
    proj_fused<<<768, 256, 0, stream>>>(Qb, Kb, Wt, bq, bk, bv, Qp, Kp, Vpt);
    attn_kernel<<<1024, 256, 0, stream>>>(Qp, Kp, Vpt, mask, Oa);
    ffn_gemm<<<256, 256, 0, stream>>>(Oa, Wt + 3 * 262144, bo, Yb);
    ln_kernel<<<2048, 256, 0, stream>>>(Yb, gamma, beta, out);
}

// Round 4
// 165.609 us; speedup vs baseline: 1.0713x; 1.0206x over previous
//
#include <hip/hip_runtime.h>

typedef __bf16 bf16;
typedef bf16 bf16x4 __attribute__((ext_vector_type(4)));
typedef bf16 bf16x8 __attribute__((ext_vector_type(8)));
typedef float floatx4 __attribute__((ext_vector_type(4)));

#define NB 8
#define NQ 1024
#define NK 1024
#define DIM 512
#define NH 8
#define DH 64

// async global->LDS, 16B per lane. LDS dest must be wave-uniform base + lane*16B.
__device__ __forceinline__ void async16(const void* g, void* l) {
    __builtin_amdgcn_global_load_lds(
        (const __attribute__((address_space(1))) unsigned int*)(unsigned long long)(g),
        (__attribute__((address_space(3))) unsigned int*)(unsigned long long)(l),
        16, 0, 0);
}

// ---------------------------------------------------------------------------
// prep_fused: blocks [0,4096): cast Q,K fp32->bf16 (float4 vectorized);
//             blocks [4096,4352): Wt[w][n][k] = (bf16)W[k][n], LDS 64x64 tiles.
// ---------------------------------------------------------------------------
__global__ __launch_bounds__(256) void prep_fused(
    const float* __restrict__ Q, const float* __restrict__ K,
    const float* __restrict__ Wq, const float* __restrict__ Wk,
    const float* __restrict__ Wv, const float* __restrict__ Wo,
    bf16* __restrict__ Qb, bf16* __restrict__ Kb, bf16* __restrict__ Wt)
{
    __shared__ bf16 Tl[64][68];
    const int bid = blockIdx.x;
    if (bid < 4096) {
        const int i = bid * 256 + threadIdx.x;   // float4 index
        float4 a = ((const float4*)Q)[i];
        float4 c = ((const float4*)K)[i];
        bf16x4 qa = {(bf16)a.x, (bf16)a.y, (bf16)a.z, (bf16)a.w};
        bf16x4 ka = {(bf16)c.x, (bf16)c.y, (bf16)c.z, (bf16)c.w};
        *(bf16x4*)(Qb + (size_t)i * 4) = qa;
        *(bf16x4*)(Kb + (size_t)i * 4) = ka;
    } else {
        const int bid2 = bid - 4096;
        const int w = bid2 >> 6;
        const int bx = bid2 & 7, by = (bid2 >> 3) & 7;
        const float* W = (w == 0) ? Wq : (w == 1) ? Wk : (w == 2) ? Wv : Wo;
        bf16* out = Wt + (size_t)w * DIM * DIM;
        const int k0 = bx * 64, n0 = by * 64;
        const int tx = threadIdx.x & 15, ty = threadIdx.x >> 4;
        for (int pass = 0; pass < 4; ++pass) {
            int k = ty + pass * 16;
            float4 v = *(const float4*)&W[(size_t)(k0 + k) * DIM + n0 + tx * 4];
            Tl[tx * 4 + 0][k] = (bf16)v.x;
            Tl[tx * 4 + 1][k] = (bf16)v.y;
            Tl[tx * 4 + 2][k] = (bf16)v.z;
            Tl[tx * 4 + 3][k] = (bf16)v.w;
        }
        __syncthreads();
        for (int pass = 0; pass < 4; ++pass) {
            int n = ty + pass * 16;
            bf16x4 ov = *(const bf16x4*)&Tl[n][tx * 4];
            *(bf16x4*)&out[(size_t)(n0 + n) * DIM + k0 + tx * 4] = ov;
        }
    }
}

// ---------------------------------------------------------------------------
// proj_fused: 128x64 tiles (M=128, N=64), BK=64, XOR-swizzled async staging,
// m-minor block mapping. LDS 48 KB -> 3 blocks/CU (was 64 KB -> 2/CU with a
// half-empty tail round at grid 768). Grid 1536 = exactly 6/CU, 3 waves/SIMD.
// Wave grid 2x2, wave tile 64x32, acc[4][2].
// blocks [0,512):    Q proj -> Qp head layout [b,h,q,64], PRE-SCALED by
//                    SC = 1/(sqrt(64)*0.1)*log2(e) so attn S is exp2-ready.
// blocks [512,1536): KV proj: n<512 -> Kp head layout; n>=512 -> Vpt
//                    [b,h,d,1024] via in-LDS transpose (coalesced stores).
// ---------------------------------------------------------------------------
__global__ __launch_bounds__(256) void proj_fused(
    const bf16* __restrict__ Qb, const bf16* __restrict__ Kb,
    const bf16* __restrict__ Wt,
    const float* __restrict__ bq, const float* __restrict__ bk,
    const float* __restrict__ bv,
    bf16* __restrict__ Qp, bf16* __restrict__ Kp, bf16* __restrict__ Vpt)
{
    // 48 KB: A0(16K) | A1(16K) | B0(8K) | B1(8K)   (bf16 units: 8192|8192|4096|4096)
    __shared__ __attribute__((aligned(16))) bf16 sh[24576];
    const int t = threadIdx.x;
    const int wave = t >> 6, lane = t & 63, quad = lane >> 4, l16 = lane & 15;
    const int wr = wave >> 1, wc = wave & 1;
    const int bid = blockIdx.x;
    const bool isQ = bid < 512;
    const bf16* A; const bf16* W; int m0, n0;
    if (isQ) { A = Qb; W = Wt;             m0 = (bid & 63) * 128;  n0 = (bid >> 6) * 64; }
    else     { int b2 = bid - 512;
               A = Kb; W = Wt + 512 * DIM; m0 = (b2 & 63) * 128;   n0 = (b2 >> 6) * 64; }

    const int r1 = t >> 3, s1 = t & 7;
    const int p1 = s1 ^ (r1 & 7);          // rows r1+32j keep row&7
    const bf16* aSrc = A + (size_t)(m0 + r1) * DIM + p1 * 8;
    const bf16* wSrc = W + (size_t)(n0 + r1) * DIM + p1 * 8;

    floatx4 acc[4][2];
    for (int i = 0; i < 4; ++i)
        for (int j = 0; j < 2; ++j) acc[i][j] = (floatx4){0.f, 0.f, 0.f, 0.f};

    // prologue: issue kt=0 into buf 0
    #pragma unroll
    for (int j = 0; j < 4; ++j)
        async16(aSrc + (size_t)j * 32 * DIM, sh + (t + j * 256) * 8);
    #pragma unroll
    for (int j = 0; j < 2; ++j)
        async16(wSrc + (size_t)j * 32 * DIM, sh + 16384 + (t + j * 256) * 8);

    for (int kt = 0; kt < 8; ++kt) {
        __syncthreads();   // tile kt loads done; all waves done with other buf
        const int cur = kt & 1;
        bf16* Acur = sh + cur * 8192;
        bf16* Bcur = sh + 16384 + cur * 4096;
        if (kt < 7) {
            bf16* Anxt = sh + (1 - cur) * 8192;
            bf16* Bnxt = sh + 16384 + (1 - cur) * 4096;
            const int ko = (kt + 1) * 64;
            #pragma unroll
            for (int j = 0; j < 4; ++j)
                async16(aSrc + ko + (size_t)j * 32 * DIM, Anxt + (t + j * 256) * 8);
            #pragma unroll
            for (int j = 0; j < 2; ++j)
                async16(wSrc + ko + (size_t)j * 32 * DIM, Bnxt + (t + j * 256) * 8);
        }
        #pragma unroll
        for (int ks = 0; ks < 2; ++ks) {
            bf16x8 af[4], bfr[2];
            #pragma unroll
            for (int mi = 0; mi < 4; ++mi) {
                const int row = wr * 64 + mi * 16 + l16;
                af[mi] = *(const bf16x8*)(Acur + row * 64 + (((ks * 4 + quad) ^ (row & 7)) << 3));
            }
            #pragma unroll
            for (int ni = 0; ni < 2; ++ni) {
                const int row = wc * 32 + ni * 16 + l16;
                bfr[ni] = *(const bf16x8*)(Bcur + row * 64 + (((ks * 4 + quad) ^ (row & 7)) << 3));
            }
            #pragma unroll
            for (int mi = 0; mi < 4; ++mi)
                #pragma unroll
                for (int ni = 0; ni < 2; ++ni)
                    acc[mi][ni] = __builtin_amdgcn_mfma_f32_16x16x32_bf16(
                        af[mi], bfr[ni], acc[mi][ni], 0, 0, 0);
        }
    }

    const bool isV = (!isQ) && (n0 >= 512);
    if (!isV) {
        bf16* out = isQ ? Qp : Kp;
        const float* bias = isQ ? bq : bk;
        const float qscale = isQ ? 1.8033688f : 1.0f;   // SC folded into Qp
        for (int ni = 0; ni < 2; ++ni) {
            const int n = n0 + wc * 32 + ni * 16 + l16;
            const float bb = bias[n];
            const int hd = n >> 6, d = n & 63;
            for (int mi = 0; mi < 4; ++mi) {
                for (int r = 0; r < 4; ++r) {
                    const int m = m0 + wr * 64 + mi * 16 + quad * 4 + r;
                    const int b = m >> 10, q = m & 1023;
                    out[((size_t)(b * 8 + hd) * 1024 + q) * 64 + d] =
                        (bf16)((acc[mi][ni][r] + bb) * qscale);
                }
            }
        }
    } else {
        // dump tile (+bias) to LDS as Tb[n][m] (n local 0..63, 16 KB) with
        // chunk-XOR swizzle, then store coalesced rows of Vpt [b,h,d,1024]
        __syncthreads();
        for (int ni = 0; ni < 2; ++ni) {
            const int n = wc * 32 + ni * 16 + l16;           // local n 0..63
            const float bb = bv[n0 + n - 512];
            for (int mi = 0; mi < 4; ++mi) {
                const int mb = wr * 64 + mi * 16 + quad * 4;  // local m base (r=0..3)
                const int slot = ((mb >> 3) ^ (n & 15));
                bf16x4 pk = {(bf16)(acc[mi][ni][0] + bb), (bf16)(acc[mi][ni][1] + bb),
                             (bf16)(acc[mi][ni][2] + bb), (bf16)(acc[mi][ni][3] + bb)};
                *(bf16x4*)(sh + n * 128 + slot * 8 + (mb & 7)) = pk;
            }
        }
        __syncthreads();
        const int n = t >> 2, hf = t & 3;                     // 4 threads/row
        const int nv = n0 + n - 512, hd = nv >> 6, d = nv & 63;
        const int b = m0 >> 10, qb = m0 & 1023;
        bf16* dst = Vpt + ((size_t)(b * 8 + hd) * 64 + d) * 1024 + qb;
        #pragma unroll
        for (int j = 0; j < 4; ++j) {
            const int ch = hf * 4 + j;                        // 16 chunks of 8 m
            const int slot = ch ^ (n & 15);
            bf16x8 v8 = *(const bf16x8*)(sh + n * 128 + slot * 8);
            *(bf16x8*)(dst + ch * 8) = v8;
        }
    }
}

// ---------------------------------------------------------------------------
// attn: flash attention per (b,h). 1024 blocks x 4 waves, 64 q/block,
// 16 q/wave (4096 waves, LDS 40KB -> 4 blocks/CU). 16x16x32 MFMA, S^T
// trick (A=K, B=Q). Q pre-scaled in proj -> P = exp2(S) directly.
// Mask: 1-load + __all ballot fast path (uniform branch).
// Denominator: mfma(P, ones) row-sum on the matrix pipe (no VALU adds,
// no epilogue shuffles). K/V LDS double-buffer via global_load_lds.
// ---------------------------------------------------------------------------
__global__ __launch_bounds__(256) void attn_kernel(
    const bf16* __restrict__ Qp, const bf16* __restrict__ Kp,
    const bf16* __restrict__ Vpt, const int* __restrict__ mask,
    bf16* __restrict__ Oa)
{
    const int bh = blockIdx.x & 63, qblk = blockIdx.x >> 6;  // qblk 0..15
    const int b = bh >> 3, hd = bh & 7;
    const int t = threadIdx.x;
    const int wave = t >> 6, lane = t & 63, quad = lane >> 4, l16 = lane & 15;

    __shared__ __attribute__((aligned(16))) bf16 Kt[2][64 * 64];
    __shared__ __attribute__((aligned(16))) bf16 Vt[2][64 * 64];
    __shared__ __attribute__((aligned(16))) bf16 Pl[4][16 * 64];

    const bf16* Qbase = Qp + ((size_t)bh * NQ + qblk * 64 + wave * 16) * DH;
    const bf16* Kbase = Kp + (size_t)bh * NK * DH;
    const bf16* Vbase = Vpt + (size_t)bh * DH * NK;
    const int* mrow = mask + b * NK;

    // Q B-frags (col=q=l16, k = hh*32 + quad*8 + j), kept in regs
    bf16x8 qf[2];
    #pragma unroll
    for (int hh = 0; hh < 2; ++hh)
        qf[hh] = *(const bf16x8*)(Qbase + (size_t)l16 * DH + hh * 32 + quad * 8);

    // all-ones B-frag for the denominator row-sum MFMA
    bf16x8 onesv;
    #pragma unroll
    for (int j = 0; j < 8; ++j) onesv[j] = (bf16)1.0f;

    floatx4 o[4];
    floatx4 osum = (floatx4){0.f, 0.f, 0.f, 0.f};
    #pragma unroll
    for (int i = 0; i < 4; ++i) o[i] = (floatx4){0.f, 0.f, 0.f, 0.f};

    const int r1 = t >> 3, s1 = t & 7;
    const int p1 = s1 ^ (r1 & 7);          // (r1+32)&7 == r1&7
    const bf16* kSrc = Kbase + r1 * 64 + p1 * 8;            // + kt*4096
    const bf16* vSrc = Vbase + (size_t)r1 * 1024 + p1 * 8;  // + kt*64

    // prologue: issue tile 0 into buf 0
    async16(kSrc, Kt[0] + t * 8);
    async16(kSrc + 32 * 64, Kt[0] + (t + 256) * 8);
    async16(vSrc, Vt[0] + t * 8);
    async16(vSrc + (size_t)32 * 1024, Vt[0] + (t + 256) * 8);

    for (int kt = 0; kt < NK / 64; ++kt) {
        __syncthreads();   // tile kt loads complete; all waves done with other buf
        const int cur = kt & 1;
        if (kt < NK / 64 - 1) {
            const int nxt = 1 - cur;
            async16(kSrc + (kt + 1) * 4096, Kt[nxt] + t * 8);
            async16(kSrc + (kt + 1) * 4096 + 32 * 64, Kt[nxt] + (t + 256) * 8);
            async16(vSrc + (kt + 1) * 64, Vt[nxt] + t * 8);
            async16(vSrc + (kt + 1) * 64 + (size_t)32 * 1024, Vt[nxt] + (t + 256) * 8);
        }

        // K A-frags (lane = key-within-subtile), conflict-free quad-spread
        bf16x8 kb[4][2];
        #pragma unroll
        for (int sub = 0; sub < 4; ++sub) {
            const int rowk = sub * 16 + l16;
            kb[sub][0] = *(const bf16x8*)(Kt[cur] + rowk * 64 + ((quad ^ (rowk & 7)) << 3));
            kb[sub][1] = *(const bf16x8*)(Kt[cur] + rowk * 64 + (((quad + 4) ^ (rowk & 7)) << 3));
        }
        // S^T = K Q^T: C col = q (l16), row = key-within-sub (quad*4+r)
        floatx4 sf[4];
        __builtin_amdgcn_s_setprio(1);
        #pragma unroll
        for (int sub = 0; sub < 4; ++sub) {
            floatx4 s = {0.f, 0.f, 0.f, 0.f};
            s = __builtin_amdgcn_mfma_f32_16x16x32_bf16(kb[sub][0], qf[0], s, 0, 0, 0);
            s = __builtin_amdgcn_mfma_f32_16x16x32_bf16(kb[sub][1], qf[1], s, 0, 0, 0);
            sf[sub] = s;
        }
        __builtin_amdgcn_s_setprio(0);

        // mask: wave-uniform fast path (1 dword/lane + ballot per 64-key tile)
        const int mv = mrow[kt * 64 + lane];
        if (!__all(mv != 0)) {
            #pragma unroll
            for (int sub = 0; sub < 4; ++sub) {
                const int4 m4 = *(const int4*)&mrow[kt * 64 + sub * 16 + quad * 4];
                if (!m4.x) sf[sub][0] = -3.0e38f;
                if (!m4.y) sf[sub][1] = -3.0e38f;
                if (!m4.z) sf[sub][2] = -3.0e38f;
                if (!m4.w) sf[sub][3] = -3.0e38f;
            }
        }
        // P = exp2(S') (scale pre-folded into Qp)
        #pragma unroll
        for (int sub = 0; sub < 4; ++sub) {
            sf[sub][0] = __builtin_amdgcn_exp2f(sf[sub][0]);
            sf[sub][1] = __builtin_amdgcn_exp2f(sf[sub][1]);
            sf[sub][2] = __builtin_amdgcn_exp2f(sf[sub][2]);
            sf[sub][3] = __builtin_amdgcn_exp2f(sf[sub][3]);
        }
        // P -> Pl[q][key]: packed b64 writes, XOR part-swizzle
        #pragma unroll
        for (int sub = 0; sub < 4; ++sub) {
            bf16x4 pk = {(bf16)sf[sub][0], (bf16)sf[sub][1],
                         (bf16)sf[sub][2], (bf16)sf[sub][3]};
            const int slot = (sub * 2 + (quad >> 1)) ^ (l16 & 7);
            *(bf16x4*)&Pl[wave][l16 * 64 + slot * 8 + (quad & 1) * 4] = pk;
        }
        bf16x8 af[2];
        #pragma unroll
        for (int hh = 0; hh < 2; ++hh) {
            const int slot = (hh * 4 + quad) ^ (l16 & 7);
            af[hh] = *(const bf16x8*)&Pl[wave][l16 * 64 + slot * 8];
        }
        // O += P V; denominator via mfma(P, ones) on the same pipe
        __builtin_amdgcn_s_setprio(1);
        osum = __builtin_amdgcn_mfma_f32_16x16x32_bf16(af[0], onesv, osum, 0, 0, 0);
        osum = __builtin_amdgcn_mfma_f32_16x16x32_bf16(af[1], onesv, osum, 0, 0, 0);
        #pragma unroll
        for (int dsub = 0; dsub < 4; ++dsub) {
            const int rowd = dsub * 16 + l16;
            bf16x8 v0 = *(const bf16x8*)(Vt[cur] + rowd * 64 + ((quad ^ (rowd & 7)) << 3));
            bf16x8 v1 = *(const bf16x8*)(Vt[cur] + rowd * 64 + (((quad + 4) ^ (rowd & 7)) << 3));
            o[dsub] = __builtin_amdgcn_mfma_f32_16x16x32_bf16(af[0], v0, o[dsub], 0, 0, 0);
            o[dsub] = __builtin_amdgcn_mfma_f32_16x16x32_bf16(af[1], v1, o[dsub], 0, 0, 0);
        }
        __builtin_amdgcn_s_setprio(0);
    }

    // osum[r] = full denominator for q = quad*4 + r (replicated over l16)
    float linv[4];
    #pragma unroll
    for (int r = 0; r < 4; ++r) linv[r] = 1.f / osum[r];
    for (int dsub = 0; dsub < 4; ++dsub) {
        for (int r = 0; r < 4; ++r) {
            const int q = qblk * 64 + wave * 16 + quad * 4 + r;
            const int col = hd * 64 + dsub * 16 + l16;
            Oa[((size_t)(b * NQ + q)) * DIM + col] = (bf16)(o[dsub][r] * linv[r]);
        }
    }
}

// ---------------------------------------------------------------------------
// ffn_gemm: 128x64 tiles (M=128, N=64), BK=64, XOR-swizzled staging,
// m-minor mapping, K-loop double-buffer. Grid 512 (was 256 = 1 wave/SIMD;
// now 2 blocks/CU, 2 waves/SIMD). LDS 48 KB. Wave tile 64x32, acc[4][2].
// Yb (bf16) = Oa + relu(Oa @ Wo^T + bo).
// ---------------------------------------------------------------------------
__global__ __launch_bounds__(256) void ffn_gemm(
    const bf16* __restrict__ Oa, const bf16* __restrict__ W,
    const float* __restrict__ bias, bf16* __restrict__ Yb)
{
    __shared__ __attribute__((aligned(16))) bf16 sh[24576];  // 48 KB: A0|A1|B0|B1
    const int t = threadIdx.x;
    const int wave = t >> 6, lane = t & 63, quad = lane >> 4, l16 = lane & 15;
    const int wr = wave >> 1, wc = wave & 1;
    const int m0 = (blockIdx.x & 63) * 128, n0 = (blockIdx.x >> 6) * 64;

    const int r1 = t >> 3, s1 = t & 7;
    const int p1 = s1 ^ (r1 & 7);
    const bf16* aSrc = Oa + (size_t)(m0 + r1) * DIM + p1 * 8;
    const bf16* wSrc = W  + (size_t)(n0 + r1) * DIM + p1 * 8;

    floatx4 acc[4][2];
    for (int i = 0; i < 4; ++i)
        for (int j = 0; j < 2; ++j) acc[i][j] = (floatx4){0.f, 0.f, 0.f, 0.f};

    #pragma unroll
    for (int j = 0; j < 4; ++j)
        async16(aSrc + (size_t)j * 32 * DIM, sh + (t + j * 256) * 8);
    #pragma unroll
    for (int j = 0; j < 2; ++j)
        async16(wSrc + (size_t)j * 32 * DIM, sh + 16384 + (t + j * 256) * 8);

    for (int kt = 0; kt < 8; ++kt) {
        __syncthreads();
        const int cur = kt & 1;
        bf16* Acur = sh + cur * 8192;
        bf16* Bcur = sh + 16384 + cur * 4096;
        if (kt < 7) {
            bf16* Anxt = sh + (1 - cur) * 8192;
            bf16* Bnxt = sh + 16384 + (1 - cur) * 4096;
            const int ko = (kt + 1) * 64;
            #pragma unroll
            for (int j = 0; j < 4; ++j)
                async16(aSrc + ko + (size_t)j * 32 * DIM, Anxt + (t + j * 256) * 8);
            #pragma unroll
            for (int j = 0; j < 2; ++j)
                async16(wSrc + ko + (size_t)j * 32 * DIM, Bnxt + (t + j * 256) * 8);
        }
        #pragma unroll
        for (int ks = 0; ks < 2; ++ks) {
            bf16x8 af[4], bfr[2];
            #pragma unroll
            for (int mi = 0; mi < 4; ++mi) {
                const int row = wr * 64 + mi * 16 + l16;
                af[mi] = *(const bf16x8*)(Acur + row * 64 + (((ks * 4 + quad) ^ (row & 7)) << 3));
            }
            #pragma unroll
            for (int ni = 0; ni < 2; ++ni) {
                const int row = wc * 32 + ni * 16 + l16;
                bfr[ni] = *(const bf16x8*)(Bcur + row * 64 + (((ks * 4 + quad) ^ (row & 7)) << 3));
            }
            #pragma unroll
            for (int mi = 0; mi < 4; ++mi)
                #pragma unroll
                for (int ni = 0; ni < 2; ++ni)
                    acc[mi][ni] = __builtin_amdgcn_mfma_f32_16x16x32_bf16(
                        af[mi], bfr[ni], acc[mi][ni], 0, 0, 0);
        }
    }

    for (int ni = 0; ni < 2; ++ni) {
        const int n = n0 + wc * 32 + ni * 16 + l16;
        const float bb = bias[n];
        for (int mi = 0; mi < 4; ++mi) {
            for (int r = 0; r < 4; ++r) {
                const int m = m0 + wr * 64 + mi * 16 + quad * 4 + r;
                const float ov = (float)Oa[(size_t)m * DIM + n];
                Yb[(size_t)m * DIM + n] = (bf16)(ov + fmaxf(acc[mi][ni][r] + bb, 0.f));
            }
        }
    }
}

// ---------------------------------------------------------------------------
// ln: LayerNorm over last dim (512). One wave per row; bf16 in, fp32 out.
// Each lane owns 8 contiguous cols (one bf16x8 load).
// ---------------------------------------------------------------------------
__global__ __launch_bounds__(256) void ln_kernel(
    const bf16* __restrict__ Y, const float* __restrict__ gamma,
    const float* __restrict__ beta, float* __restrict__ out)
{
    const int row  = blockIdx.x * 4 + (threadIdx.x >> 6);
    const int lane = threadIdx.x & 63;
    bf16x8 v = *(const bf16x8*)(Y + (size_t)row * DIM + lane * 8);
    float f[8];
    float s = 0.f, sq = 0.f;
    #pragma unroll
    for (int j = 0; j < 8; ++j) {
        f[j] = (float)v[j];
        s += f[j];
        sq += f[j] * f[j];
    }
    for (int mk = 32; mk >= 1; mk >>= 1) {
        s  += __shfl_xor(s,  mk, 64);
        sq += __shfl_xor(sq, mk, 64);
    }
    const float mu  = s * (1.f / 512.f);
    const float var = sq * (1.f / 512.f) - mu * mu;
    const float inv = rsqrtf(var + 1e-5f);
    float4 g1 = ((const float4*)gamma)[lane * 2];
    float4 g2 = ((const float4*)gamma)[lane * 2 + 1];
    float4 b1 = ((const float4*)beta)[lane * 2];
    float4 b2 = ((const float4*)beta)[lane * 2 + 1];
    float4 o1, o2;
    o1.x = (f[0] - mu) * inv * g1.x + b1.x;
    o1.y = (f[1] - mu) * inv * g1.y + b1.y;
    o1.z = (f[2] - mu) * inv * g1.z + b1.z;
    o1.w = (f[3] - mu) * inv * g1.w + b1.w;
    o2.x = (f[4] - mu) * inv * g2.x + b2.x;
    o2.y = (f[5] - mu) * inv * g2.y + b2.y;
    o2.z = (f[6] - mu) * inv * g2.z + b2.z;
    o2.w = (f[7] - mu) * inv * g2.w + b2.w;
    float* orow = out + (size_t)row * DIM;
    ((float4*)orow)[lane * 2]     = o1;
    ((float4*)orow)[lane * 2 + 1] = o2;
}

// ---------------------------------------------------------------------------
extern "C" void kernel_launch(void* const* d_in, const int* in_sizes, int n_in,
                              void* d_out, int out_size, void* d_ws, size_t ws_size,
                              hipStream_t stream) {
    const float* Q  = (const float*)d_in[0];
    const float* K  = (const float*)d_in[1];
    const int*   mask = (const int*)d_in[2];
    const float* Wq = (const float*)d_in[3];
    const float* bq = (const float*)d_in[4];
    const float* Wk = (const float*)d_in[5];
    const float* bk = (const float*)d_in[6];
    const float* Wv = (const float*)d_in[7];
    const float* bv = (const float*)d_in[8];
    const float* Wo = (const float*)d_in[9];
    const float* bo = (const float*)d_in[10];
    const float* gamma = (const float*)d_in[11];
    const float* beta  = (const float*)d_in[12];

    char* ws = (char*)d_ws;
    bf16* Wt  = (bf16*)(ws);                   // 2 MB (4 x 512x512 bf16, transposed)
    bf16* Qb  = (bf16*)(ws + 2097152);         // 8 MB
    bf16* Kb  = (bf16*)(ws + 10485760);        // 8 MB
    bf16* Qp  = (bf16*)(ws + 18874368);        // 8 MB  [b,h,q,64] (pre-scaled)
    bf16* Kp  = (bf16*)(ws + 27262976);        // 8 MB  [b,h,k,64]
    bf16* Vpt = (bf16*)(ws + 35651584);        // 8 MB  [b,h,d,1024]
    bf16* Oa  = (bf16*)(ws + 44040192);        // 8 MB  [b,q,512]
    bf16* Yb  = (bf16*)(ws + 52428800);        // 8 MB  [b,q,512] bf16
    float* out = (float*)d_out;

    prep_fused<<<4352, 256, 0, stream>>>(Q, K, Wq, Wk, Wv, Wo, Qb, Kb, Wt);
    proj_fused<<<1536, 256, 0, stream>>>(Qb, Kb, Wt, bq, bk, bv, Qp, Kp, Vpt);
    attn_kernel<<<1024, 256, 0, stream>>>(Qp, Kp, Vpt, mask, Oa);
    ffn_gemm<<<512, 256, 0, stream>>>(Oa, Wt + 3 * 262144, bo, Yb);
    ln_kernel<<<2048, 256, 0, stream>>>(Yb, gamma, beta, out);
}